// Round 11
// baseline (708.462 us; speedup 1.0000x reference)
//
#include <hip/hip_runtime.h>
#include <stdint.h>

#define B_ 64
#define T_ 16
#define D0 1024
#define H_ 2048
#define G4 8192  // 4*H
#define NB 256   // persistent blocks (one per CU)

typedef unsigned short u16;
typedef unsigned long long u64;
typedef __attribute__((ext_vector_type(4))) float f32x4;
typedef __attribute__((ext_vector_type(8))) short bf16x8;

__device__ __forceinline__ u16 f2bf(float f) {
  unsigned int u = __builtin_bit_cast(unsigned int, f);
  unsigned int r = (u + 0x7FFFu + ((u >> 16) & 1u)) >> 16;
  return (u16)r;
}
__device__ __forceinline__ short f2bf_s(float f) { return (short)f2bf(f); }

__device__ __forceinline__ void gld_lds16(const void* g, void* l) {
  __builtin_amdgcn_global_load_lds(
      (const __attribute__((address_space(1))) void*)g,
      (__attribute__((address_space(3))) void*)l, 16, 0, 0);
}

__device__ __forceinline__ bf16x8 frag_from_u4(uint4 q) {
  return __builtin_bit_cast(bf16x8, q);
}

// ---------------- fp32 -> bf16 bulk conversion (RTN) ----------------
__global__ __launch_bounds__(256) void k_f32_to_bf16(
    const float* __restrict__ src, u16* __restrict__ dst, int n8) {
  int i = blockIdx.x * 256 + threadIdx.x;
  int stride = gridDim.x * 256;
  const float4* s = (const float4*)src;
  uint4* d = (uint4*)dst;
  for (; i < n8; i += stride) {
    float4 a = s[2 * i], b = s[2 * i + 1];
    uint4 o;
    o.x = f2bf(a.x) | ((unsigned)f2bf(a.y) << 16);
    o.y = f2bf(a.z) | ((unsigned)f2bf(a.w) << 16);
    o.z = f2bf(b.x) | ((unsigned)f2bf(b.y) << 16);
    o.w = f2bf(b.z) | ((unsigned)f2bf(b.w) << 16);
    d[i] = o;
  }
}

// ---------------- combined bias: b_ih + b_hh, 4 layers ----------------
__global__ __launch_bounds__(256) void k_bias(
    const float* __restrict__ bih0, const float* __restrict__ bhh0,
    const float* __restrict__ bihr, const float* __restrict__ bhhr,
    float* __restrict__ bias) {
  int i = blockIdx.x * 256 + threadIdx.x;
  if (i >= 4 * G4) return;
  int l = i >> 13, j = i & (G4 - 1);
  float a = (l == 0) ? bih0[j] : bihr[(l - 1) * G4 + j];
  float b = (l == 0) ? bhh0[j] : bhhr[(l - 1) * G4 + j];
  bias[i] = a + b;
}

// ---- stage x [B,T,D0] fp32 -> chunk layout: Ax16[(t*128 + k/8)*64 + b] ----
__global__ __launch_bounds__(256) void k_stage_x(
    const float* __restrict__ x, uint4* __restrict__ A16) {
  int i = blockIdx.x * 256 + threadIdx.x;
  if (i >= T_ * (D0 / 8) * B_) return;
  int chunk = i & 127;
  int r = i >> 7;
  int b = r & (B_ - 1), t = r >> 6;
  const float4* s = (const float4*)(x + ((size_t)(b * T_ + t)) * D0 + chunk * 8);
  float4 a0 = s[0], a1 = s[1];
  uint4 o;
  o.x = f2bf(a0.x) | ((unsigned)f2bf(a0.y) << 16);
  o.y = f2bf(a0.z) | ((unsigned)f2bf(a0.w) << 16);
  o.z = f2bf(a1.x) | ((unsigned)f2bf(a1.y) << 16);
  o.w = f2bf(a1.z) | ((unsigned)f2bf(a1.w) << 16);
  A16[((size_t)t * 128 + chunk) * 64 + b] = o;
}

// ---------------- input-projection GEMM (layer 0 only) ----------------
__global__ __launch_bounds__(256) void k_gemm_xi(
    const u16* __restrict__ A, const u16* __restrict__ W,
    const float* __restrict__ bias, float* __restrict__ C, int K, int CH) {
  __shared__ __align__(16) u16 sA[128 * 32];
  __shared__ __align__(16) u16 sB[128 * 32];
  const int tid = threadIdx.x;
  const int wave = tid >> 6;
  const int lane = tid & 63;
  const int m0 = blockIdx.y * 128;
  const int n0 = blockIdx.x * 128;
  const int wr = wave >> 1, wc = wave & 1;
  const int lr = lane & 15;
  const int kc = (lane >> 4) * 8;
  const int rowA = tid >> 2, colk = (tid & 3) * 8;

  f32x4 acc[4][4] = {};

  for (int k0 = 0; k0 < K; k0 += 32) {
#pragma unroll
    for (int iss = 0; iss < 2; ++iss) {
      int row = m0 + iss * 64 + rowA;
      int tt = row >> 6, bb = row & 63;
      int chunk = (k0 + colk) >> 3;
      gld_lds16(A + ((((size_t)tt * CH + chunk) * 64 + bb) << 3),
                sA + (iss * 64 + wave * 16) * 32);
      gld_lds16(W + (size_t)(n0 + iss * 64 + rowA) * K + k0 + colk,
                sB + (iss * 64 + wave * 16) * 32);
    }
    __syncthreads();
    bf16x8 a[4], b[4];
#pragma unroll
    for (int m = 0; m < 4; ++m)
      a[m] = *(const bf16x8*)&sA[(wr * 64 + m * 16 + lr) * 32 + kc];
#pragma unroll
    for (int n = 0; n < 4; ++n)
      b[n] = *(const bf16x8*)&sB[(wc * 64 + n * 16 + lr) * 32 + kc];
#pragma unroll
    for (int m = 0; m < 4; ++m)
#pragma unroll
      for (int n = 0; n < 4; ++n)
        acc[m][n] = __builtin_amdgcn_mfma_f32_16x16x32_bf16(a[m], b[n], acc[m][n], 0, 0, 0);
    __syncthreads();
  }

#pragma unroll
  for (int n = 0; n < 4; ++n) {
    int col = n0 + wc * 64 + n * 16 + lr;
    float bv = bias[col];
#pragma unroll
    for (int m = 0; m < 4; ++m) {
      int row0 = m0 + wr * 64 + m * 16 + ((lane >> 4) << 2);
      int t = row0 >> 6, b0 = row0 & 63;
      float4 v;
      v.x = acc[m][n][0] + bv;
      v.y = acc[m][n][1] + bv;
      v.z = acc[m][n][2] + bv;
      v.w = acc[m][n][3] + bv;
      *(float4*)&C[((size_t)t * G4 + col) * B_ + b0] = v;
    }
  }
}

// ---------------- persistent ALL-LAYER recurrent kernel ----------------
// One kernel, internal layer loop. Per layer: R10's validated structure
// (VGPR-resident Whh + W_ih,next; fused next-layer xi; per-block one-shot
// flags; write-through h stores; cached h reads). xi is block-local across
// layers (block j reads only rows it wrote itself). Per-layer h buffers ->
// no address reuse within a call -> single entry fence suffices.
// t=0 of each layer runs BEFORE that layer's weight preload (needs none).
__global__ __launch_bounds__(256, 1) void k_lstm_all(
    const float* __restrict__ whh0,  // [8192][2048] fp32
    const float* __restrict__ whhr,  // [3][8192][2048] fp32
    const float* __restrict__ wihr,  // [3][8192][2048] fp32
    float* __restrict__ xiA,         // [T][G4][B] fp32 (layer-0 xi, gemm out)
    float* __restrict__ xiB,         // [T][G4][B] fp32 scratch
    u16* __restrict__ hbase,         // 4 x [T][256][64] 16B-chunk buffers
    float* __restrict__ out32,       // [B][T][2048] fp32 final
    const float* __restrict__ bias,  // [4][G4] combined biases
    unsigned* __restrict__ flags) {  // [4][16][256] one-shot, pre-zeroed
  __builtin_amdgcn_fence(__ATOMIC_ACQUIRE, "agent");

  __shared__ float red[4][64][33];
  __shared__ unsigned harr[64][4];
  __shared__ float hfar[64][9];
  __shared__ float bbuf[32];

  const int tid = threadIdx.x;
  const int wave = tid >> 6;  // K-slice index 0..3
  const int lane = tid & 63;
  const int lr = lane & 15;
  const int kc = lane >> 4;  // 0..3
  const int jb = blockIdx.x * 8;

  const int cb = tid & 63;
  const int cp = tid >> 6;
  const int j0 = 2 * cp, j1 = 2 * cp + 1;

  bf16x8 warr[2][16];
  bf16x8 wnarr[2][16];

  for (int l = 0; l < 4; ++l) {
    const bool has_next = (l < 3);
    const float* whh_l = (l == 0) ? whh0 : whhr + (size_t)(l - 1) * G4 * H_;
    const float* wih_next = has_next ? wihr + (size_t)l * G4 * H_ : nullptr;
    const float* xi_in = (l & 1) ? xiB : xiA;
    float* xi_next = (l & 1) ? xiA : xiB;
    u16* hfr = hbase + (size_t)l * T_ * 256 * 64 * 8;  // 8 u16 per chunk
    const uint4* H16 = (const uint4*)hfr;
    u64* hq = (u64*)hfr;
    unsigned* flg = flags + (size_t)l * 16 * 256;
    float* o32 = (l == 3) ? out32 : nullptr;
    const float* bias_next = bias + (size_t)((l + 1) & 3) * G4;

    float cst0 = 0.f, cst1 = 0.f;

    auto xi_writeback = [&](int tt) {
      __syncthreads();
#pragma unroll
      for (int j = 0; j < 8; ++j) {
        int e = tid + 256 * j;
        int b = e & 63, r = e >> 6;
        float v = red[0][b][r] + red[1][b][r] + red[2][b][r] + red[3][b][r] + bbuf[r];
        xi_next[((size_t)tt * G4 + (r >> 3) * H_ + jb + (r & 7)) * (size_t)B_ + b] = v;
      }
      __syncthreads();
    };

    auto do_step = [&](int t) {
      // xi loads: coalesced, issued before the flag wait
      float xv0[4], xv1[4];
      {
        const float* xp = xi_in + (size_t)t * G4 * B_ + (size_t)(jb + j0) * B_ + cb;
#pragma unroll
        for (int g = 0; g < 4; ++g) {
          xv0[g] = xp[(size_t)g * H_ * B_];
          xv1[g] = xp[(size_t)g * H_ * B_ + B_];
        }
      }

      f32x4 acc[4][2] = {};
      f32x4 facc[4][2] = {};
      if (t > 0) {
        const unsigned* fp = flg + (size_t)(t - 1) * 256 + wave * 64 + lane;
        while (__hip_atomic_load(fp, __ATOMIC_RELAXED,
                                 __HIP_MEMORY_SCOPE_SYSTEM) == 0u)
          __builtin_amdgcn_s_sleep(1);
        asm volatile("" ::: "memory");  // keep cached h loads below the spin

        const size_t base = ((size_t)(t - 1) * 256 + wave * 64 + kc) * 64 + lr;
        uint4 pre[4][4];
#pragma unroll
        for (int d = 0; d < 4; ++d)
#pragma unroll
          for (int m = 0; m < 4; ++m)
            pre[d][m] = H16[base + (size_t)d * 256 + m * 16];
#pragma unroll
        for (int kk = 0; kk < 16; ++kk) {
          const int slot = kk & 3;
          bf16x8 af[4];
#pragma unroll
          for (int m = 0; m < 4; ++m)
            af[m] = frag_from_u4(pre[slot][m]);
          if (kk + 4 < 16) {
#pragma unroll
            for (int m = 0; m < 4; ++m)
              pre[slot][m] = H16[base + (size_t)(kk + 4) * 256 + m * 16];
          }
#pragma unroll
          for (int m = 0; m < 4; ++m) {
            acc[m][0] = __builtin_amdgcn_mfma_f32_16x16x32_bf16(af[m], warr[0][kk], acc[m][0], 0, 0, 0);
            acc[m][1] = __builtin_amdgcn_mfma_f32_16x16x32_bf16(af[m], warr[1][kk], acc[m][1], 0, 0, 0);
          }
          if (has_next) {
#pragma unroll
            for (int m = 0; m < 4; ++m) {
              facc[m][0] = __builtin_amdgcn_mfma_f32_16x16x32_bf16(af[m], wnarr[0][kk], facc[m][0], 0, 0, 0);
              facc[m][1] = __builtin_amdgcn_mfma_f32_16x16x32_bf16(af[m], wnarr[1][kk], facc[m][1], 0, 0, 0);
            }
          }
        }
      }

      // recurrent partials -> LDS; 4-way reduction in cell
#pragma unroll
      for (int m = 0; m < 4; ++m)
#pragma unroll
        for (int n = 0; n < 2; ++n)
#pragma unroll
          for (int j = 0; j < 4; ++j)
            red[wave][m * 16 + kc * 4 + j][n * 16 + lr] = acc[m][n][j];
      __syncthreads();

      // LSTM cell
      {
        float s00 = red[0][cb][j0]      + red[1][cb][j0]      + red[2][cb][j0]      + red[3][cb][j0];
        float s01 = red[0][cb][8 + j0]  + red[1][cb][8 + j0]  + red[2][cb][8 + j0]  + red[3][cb][8 + j0];
        float s02 = red[0][cb][16 + j0] + red[1][cb][16 + j0] + red[2][cb][16 + j0] + red[3][cb][16 + j0];
        float s03 = red[0][cb][24 + j0] + red[1][cb][24 + j0] + red[2][cb][24 + j0] + red[3][cb][24 + j0];
        float iv = s00 + xv0[0];
        float fv = s01 + xv0[1];
        float gv = s02 + xv0[2];
        float ov = s03 + xv0[3];
        iv = 1.f / (1.f + expf(-iv));
        fv = 1.f / (1.f + expf(-fv));
        gv = tanhf(gv);
        ov = 1.f / (1.f + expf(-ov));
        cst0 = fv * cst0 + iv * gv;
        float hv0 = ov * tanhf(cst0);

        float s10 = red[0][cb][j1]      + red[1][cb][j1]      + red[2][cb][j1]      + red[3][cb][j1];
        float s11 = red[0][cb][8 + j1]  + red[1][cb][8 + j1]  + red[2][cb][8 + j1]  + red[3][cb][8 + j1];
        float s12 = red[0][cb][16 + j1] + red[1][cb][16 + j1] + red[2][cb][16 + j1] + red[3][cb][16 + j1];
        float s13 = red[0][cb][24 + j1] + red[1][cb][24 + j1] + red[2][cb][24 + j1] + red[3][cb][24 + j1];
        float iv1 = s10 + xv1[0];
        float fv1 = s11 + xv1[1];
        float gv1 = s12 + xv1[2];
        float ov1 = s13 + xv1[3];
        iv1 = 1.f / (1.f + expf(-iv1));
        fv1 = 1.f / (1.f + expf(-fv1));
        gv1 = tanhf(gv1);
        ov1 = 1.f / (1.f + expf(-ov1));
        cst1 = fv1 * cst1 + iv1 * gv1;
        float hv1 = ov1 * tanhf(cst1);

        harr[cb][cp] = (unsigned)f2bf(hv0) | ((unsigned)f2bf(hv1) << 16);
        hfar[cb][j0] = hv0;
        hfar[cb][j1] = hv1;
      }
      __syncthreads();

      // wave 0: h write-through stores, then flag (incl. t=15)
      if (tid < B_) {
        u64 q0 = (u64)harr[tid][0] | ((u64)harr[tid][1] << 32);
        u64 q1 = (u64)harr[tid][2] | ((u64)harr[tid][3] << 32);
        u64* hp = hq + ((((size_t)t * 256 + blockIdx.x) * 64 + tid) << 1);
        __hip_atomic_store(hp, q0, __ATOMIC_RELAXED, __HIP_MEMORY_SCOPE_SYSTEM);
        __hip_atomic_store(hp + 1, q1, __ATOMIC_RELAXED, __HIP_MEMORY_SCOPE_SYSTEM);
        if (o32 != nullptr) {
          float* op = o32 + ((size_t)tid * T_ + t) * H_ + jb;
          float4 v0, v1;
          v0.x = hfar[tid][0]; v0.y = hfar[tid][1]; v0.z = hfar[tid][2]; v0.w = hfar[tid][3];
          v1.x = hfar[tid][4]; v1.y = hfar[tid][5]; v1.z = hfar[tid][6]; v1.w = hfar[tid][7];
          *(float4*)op = v0;
          *(float4*)(op + 4) = v1;
        }
      }
      if (tid == 0) {
        asm volatile("s_waitcnt vmcnt(0)" ::: "memory");  // h at coherence pt
        __hip_atomic_store(flg + (size_t)t * 256 + blockIdx.x, 1u,
                           __ATOMIC_RELAXED, __HIP_MEMORY_SCOPE_SYSTEM);
      }

      // OFF critical path: xi_next(t-1) reduce + store
      if (has_next && t > 0) {
        __syncthreads();
#pragma unroll
        for (int m = 0; m < 4; ++m)
#pragma unroll
          for (int n = 0; n < 2; ++n)
#pragma unroll
            for (int j = 0; j < 4; ++j)
              red[wave][m * 16 + kc * 4 + j][n * 16 + lr] = facc[m][n][j];
        xi_writeback(t - 1);
      }
    };

    // ---- t=0 first: needs no weights; releases flag(l,0) early ----
    do_step(0);

    // ---- weight preload: fp32 global -> bf16 fragments in VGPRs ----
#pragma unroll
    for (int n = 0; n < 2; ++n) {
      int row = n * 16 + lr;
      int grow = (row >> 3) * H_ + jb + (row & 7);
      const float* wp = whh_l + (size_t)grow * H_ + wave * 512 + kc * 8;
#pragma unroll
      for (int kk = 0; kk < 16; ++kk) {
        float4 f0 = *(const float4*)(wp + kk * 32);
        float4 f1 = *(const float4*)(wp + kk * 32 + 4);
        bf16x8 w;
        w[0] = f2bf_s(f0.x); w[1] = f2bf_s(f0.y); w[2] = f2bf_s(f0.z); w[3] = f2bf_s(f0.w);
        w[4] = f2bf_s(f1.x); w[5] = f2bf_s(f1.y); w[6] = f2bf_s(f1.z); w[7] = f2bf_s(f1.w);
        warr[n][kk] = w;
      }
    }
    if (has_next) {
#pragma unroll
      for (int n = 0; n < 2; ++n) {
        int row = n * 16 + lr;
        int grow = (row >> 3) * H_ + jb + (row & 7);
        const float* wp = wih_next + (size_t)grow * H_ + wave * 512 + kc * 8;
#pragma unroll
        for (int kk = 0; kk < 16; ++kk) {
          float4 f0 = *(const float4*)(wp + kk * 32);
          float4 f1 = *(const float4*)(wp + kk * 32 + 4);
          bf16x8 w;
          w[0] = f2bf_s(f0.x); w[1] = f2bf_s(f0.y); w[2] = f2bf_s(f0.z); w[3] = f2bf_s(f0.w);
          w[4] = f2bf_s(f1.x); w[5] = f2bf_s(f1.y); w[6] = f2bf_s(f1.z); w[7] = f2bf_s(f1.w);
          wnarr[n][kk] = w;
        }
      }
      if (tid < 32) bbuf[tid] = bias_next[(tid >> 3) * H_ + jb + (tid & 7)];
    }
    __syncthreads();

    for (int t = 1; t < T_; ++t) do_step(t);

    // ---- epilogue: xi_next(15) via flag[15] ----
    if (has_next) {
      const unsigned* fp = flg + (size_t)15 * 256 + wave * 64 + lane;
      while (__hip_atomic_load(fp, __ATOMIC_RELAXED,
                               __HIP_MEMORY_SCOPE_SYSTEM) == 0u)
        __builtin_amdgcn_s_sleep(1);
      asm volatile("" ::: "memory");

      f32x4 facc[4][2] = {};
      const size_t base = ((size_t)15 * 256 + wave * 64 + kc) * 64 + lr;
      uint4 pre[2][4];
#pragma unroll
      for (int d = 0; d < 2; ++d)
#pragma unroll
        for (int m = 0; m < 4; ++m)
          pre[d][m] = H16[base + (size_t)d * 256 + m * 16];
#pragma unroll
      for (int kk = 0; kk < 16; ++kk) {
        const int slot = kk & 1;
        bf16x8 af[4];
#pragma unroll
        for (int m = 0; m < 4; ++m)
          af[m] = frag_from_u4(pre[slot][m]);
        if (kk + 2 < 16) {
#pragma unroll
          for (int m = 0; m < 4; ++m)
            pre[slot][m] = H16[base + (size_t)(kk + 2) * 256 + m * 16];
        }
#pragma unroll
        for (int m = 0; m < 4; ++m) {
          facc[m][0] = __builtin_amdgcn_mfma_f32_16x16x32_bf16(af[m], wnarr[0][kk], facc[m][0], 0, 0, 0);
          facc[m][1] = __builtin_amdgcn_mfma_f32_16x16x32_bf16(af[m], wnarr[1][kk], facc[m][1], 0, 0, 0);
        }
      }
      __syncthreads();
#pragma unroll
      for (int m = 0; m < 4; ++m)
#pragma unroll
        for (int n = 0; n < 2; ++n)
#pragma unroll
          for (int j = 0; j < 4; ++j)
            red[wave][m * 16 + kc * 4 + j][n * 16 + lr] = facc[m][n][j];
      xi_writeback(15);
    }
  }
}

extern "C" void kernel_launch(void* const* d_in, const int* in_sizes, int n_in,
                              void* d_out, int out_size, void* d_ws, size_t ws_size,
                              hipStream_t stream) {
  const float* x    = (const float*)d_in[0];
  const float* wih0 = (const float*)d_in[1];
  const float* whh0 = (const float*)d_in[2];
  const float* bih0 = (const float*)d_in[3];
  const float* bhh0 = (const float*)d_in[4];
  const float* wihr = (const float*)d_in[5];
  const float* whhr = (const float*)d_in[6];
  const float* bihr = (const float*)d_in[7];
  const float* bhhr = (const float*)d_in[8];
  float* out = (float*)d_out;

  char* ws = (char*)d_ws;
  size_t off = 0;
  auto alloc = [&](size_t bytes) -> void* {
    void* p = ws + off;
    off += (bytes + 255) & ~(size_t)255;
    return p;
  };
  u16*      wih_b = (u16*)alloc((size_t)G4 * D0 * 2);   // layer 0 only
  float*    bias  = (float*)alloc(4ull * G4 * 4);
  float*    xiA   = (float*)alloc((size_t)T_ * B_ * G4 * 4);
  float*    xiB   = (float*)alloc((size_t)T_ * B_ * G4 * 4);
  u16*      Ax    = (u16*)alloc((size_t)T_ * B_ * D0 * 2);
  u16*      hbase = (u16*)alloc(4ull * T_ * B_ * H_ * 2);  // 4 x 4MB
  unsigned* flags = (unsigned*)alloc(4ull * 16 * 256 * sizeof(unsigned));

  auto cgrid = [](int n8) { int g = (n8 + 255) / 256; return g > 8192 ? 8192 : g; };

  hipMemsetAsync(flags, 0, 4ull * 16 * 256 * sizeof(unsigned), stream);

  int n8 = (G4 * D0) / 8;
  k_f32_to_bf16<<<cgrid(n8), 256, 0, stream>>>(wih0, wih_b, n8);

  k_bias<<<(4 * G4 + 255) / 256, 256, 0, stream>>>(bih0, bhh0, bihr, bhhr, bias);
  k_stage_x<<<(T_ * (D0 / 8) * B_ + 255) / 256, 256, 0, stream>>>(x, (uint4*)Ax);

  // layer 0 input projection (the only standalone GEMM)
  {
    dim3 g(G4 / 128, (T_ * B_) / 128);
    k_gemm_xi<<<g, 256, 0, stream>>>(Ax, wih_b, bias, xiA, D0, D0 / 8);
  }

  // all 4 LSTM layers in one persistent kernel
  k_lstm_all<<<NB, 256, 0, stream>>>(whh0, whhr, wihr, xiA, xiB, hbase, out,
                                     bias, flags);
}

// Round 12
// 706.692 us; speedup vs baseline: 1.0025x; 1.0025x over previous
//
#include <hip/hip_runtime.h>
#include <stdint.h>

#define B_ 64
#define T_ 16
#define D0 1024
#define H_ 2048
#define G4 8192  // 4*H
#define NB 256   // persistent blocks (one per CU)

typedef unsigned short u16;
typedef unsigned long long u64;
typedef __attribute__((ext_vector_type(4))) float f32x4;
typedef __attribute__((ext_vector_type(8))) short bf16x8;

__device__ __forceinline__ u16 f2bf(float f) {
  unsigned int u = __builtin_bit_cast(unsigned int, f);
  unsigned int r = (u + 0x7FFFu + ((u >> 16) & 1u)) >> 16;
  return (u16)r;
}
__device__ __forceinline__ short f2bf_s(float f) { return (short)f2bf(f); }

__device__ __forceinline__ void gld_lds16(const void* g, void* l) {
  __builtin_amdgcn_global_load_lds(
      (const __attribute__((address_space(1))) void*)g,
      (__attribute__((address_space(3))) void*)l, 16, 0, 0);
}

__device__ __forceinline__ bf16x8 frag_from_u4(uint4 q) {
  return __builtin_bit_cast(bf16x8, q);
}

// ---------------- fp32 -> bf16 bulk conversion (RTN) ----------------
__global__ __launch_bounds__(256) void k_f32_to_bf16(
    const float* __restrict__ src, u16* __restrict__ dst, int n8) {
  int i = blockIdx.x * 256 + threadIdx.x;
  int stride = gridDim.x * 256;
  const float4* s = (const float4*)src;
  uint4* d = (uint4*)dst;
  for (; i < n8; i += stride) {
    float4 a = s[2 * i], b = s[2 * i + 1];
    uint4 o;
    o.x = f2bf(a.x) | ((unsigned)f2bf(a.y) << 16);
    o.y = f2bf(a.z) | ((unsigned)f2bf(a.w) << 16);
    o.z = f2bf(b.x) | ((unsigned)f2bf(b.y) << 16);
    o.w = f2bf(b.z) | ((unsigned)f2bf(b.w) << 16);
    d[i] = o;
  }
}

// ---------------- combined bias: b_ih + b_hh, 4 layers ----------------
__global__ __launch_bounds__(256) void k_bias(
    const float* __restrict__ bih0, const float* __restrict__ bhh0,
    const float* __restrict__ bihr, const float* __restrict__ bhhr,
    float* __restrict__ bias) {
  int i = blockIdx.x * 256 + threadIdx.x;
  if (i >= 4 * G4) return;
  int l = i >> 13, j = i & (G4 - 1);
  float a = (l == 0) ? bih0[j] : bihr[(l - 1) * G4 + j];
  float b = (l == 0) ? bhh0[j] : bhhr[(l - 1) * G4 + j];
  bias[i] = a + b;
}

// ---- stage x [B,T,D0] fp32 -> chunk layout: Ax16[(t*128 + k/8)*64 + b] ----
__global__ __launch_bounds__(256) void k_stage_x(
    const float* __restrict__ x, uint4* __restrict__ A16) {
  int i = blockIdx.x * 256 + threadIdx.x;
  if (i >= T_ * (D0 / 8) * B_) return;
  int chunk = i & 127;
  int r = i >> 7;
  int b = r & (B_ - 1), t = r >> 6;
  const float4* s = (const float4*)(x + ((size_t)(b * T_ + t)) * D0 + chunk * 8);
  float4 a0 = s[0], a1 = s[1];
  uint4 o;
  o.x = f2bf(a0.x) | ((unsigned)f2bf(a0.y) << 16);
  o.y = f2bf(a0.z) | ((unsigned)f2bf(a0.w) << 16);
  o.z = f2bf(a1.x) | ((unsigned)f2bf(a1.y) << 16);
  o.w = f2bf(a1.z) | ((unsigned)f2bf(a1.w) << 16);
  A16[((size_t)t * 128 + chunk) * 64 + b] = o;
}

// ---------------- input-projection GEMM (layer 0 only) ----------------
__global__ __launch_bounds__(256) void k_gemm_xi(
    const u16* __restrict__ A, const u16* __restrict__ W,
    const float* __restrict__ bias, float* __restrict__ C, int K, int CH) {
  __shared__ __align__(16) u16 sA[128 * 32];
  __shared__ __align__(16) u16 sB[128 * 32];
  const int tid = threadIdx.x;
  const int wave = tid >> 6;
  const int lane = tid & 63;
  const int m0 = blockIdx.y * 128;
  const int n0 = blockIdx.x * 128;
  const int wr = wave >> 1, wc = wave & 1;
  const int lr = lane & 15;
  const int kc = (lane >> 4) * 8;
  const int rowA = tid >> 2, colk = (tid & 3) * 8;

  f32x4 acc[4][4] = {};

  for (int k0 = 0; k0 < K; k0 += 32) {
#pragma unroll
    for (int iss = 0; iss < 2; ++iss) {
      int row = m0 + iss * 64 + rowA;
      int tt = row >> 6, bb = row & 63;
      int chunk = (k0 + colk) >> 3;
      gld_lds16(A + ((((size_t)tt * CH + chunk) * 64 + bb) << 3),
                sA + (iss * 64 + wave * 16) * 32);
      gld_lds16(W + (size_t)(n0 + iss * 64 + rowA) * K + k0 + colk,
                sB + (iss * 64 + wave * 16) * 32);
    }
    __syncthreads();
    bf16x8 a[4], b[4];
#pragma unroll
    for (int m = 0; m < 4; ++m)
      a[m] = *(const bf16x8*)&sA[(wr * 64 + m * 16 + lr) * 32 + kc];
#pragma unroll
    for (int n = 0; n < 4; ++n)
      b[n] = *(const bf16x8*)&sB[(wc * 64 + n * 16 + lr) * 32 + kc];
#pragma unroll
    for (int m = 0; m < 4; ++m)
#pragma unroll
      for (int n = 0; n < 4; ++n)
        acc[m][n] = __builtin_amdgcn_mfma_f32_16x16x32_bf16(a[m], b[n], acc[m][n], 0, 0, 0);
    __syncthreads();
  }

#pragma unroll
  for (int n = 0; n < 4; ++n) {
    int col = n0 + wc * 64 + n * 16 + lr;
    float bv = bias[col];
#pragma unroll
    for (int m = 0; m < 4; ++m) {
      int row0 = m0 + wr * 64 + m * 16 + ((lane >> 4) << 2);
      int t = row0 >> 6, b0 = row0 & 63;
      float4 v;
      v.x = acc[m][n][0] + bv;
      v.y = acc[m][n][1] + bv;
      v.z = acc[m][n][2] + bv;
      v.w = acc[m][n][3] + bv;
      *(float4*)&C[((size_t)t * G4 + col) * B_ + b0] = v;
    }
  }
}

// ---------------- persistent per-layer recurrent kernel ----------------
// R10 validated structure; ONLY change: h-load pipeline depth 2 -> 8
// (pre[8][4], 32 loads in flight/wave). At 1 block/CU we are pinned to
// 1 wave/SIMD regardless of VGPRs (launch_bounds(256,1) allows 512), so
// the deeper pipeline costs no occupancy.
__global__ __launch_bounds__(256, 1) void k_lstm_seq(
    const float* __restrict__ whh,      // [8192][2048] fp32
    const float* __restrict__ xi,       // [T][G4][B] fp32 (bias folded)
    u16* __restrict__ hfr,              // [T][256][64] x 16B chunk layout
    float* __restrict__ out32,          // null, or [B][T][2048] fp32
    unsigned* __restrict__ flg,         // [16][256] one-shot flags, zeroed
    const float* __restrict__ wih_next, // null, or [8192][2048] fp32
    const float* __restrict__ bias_next,// [G4]
    float* __restrict__ xi_next) {      // [T][G4][B] fp32 out
  __builtin_amdgcn_fence(__ATOMIC_ACQUIRE, "agent");

  __shared__ float red[4][64][33];
  __shared__ unsigned harr[64][4];
  __shared__ float hfar[64][9];
  __shared__ float bbuf[32];

  const int tid = threadIdx.x;
  const int wave = tid >> 6;  // K-slice index 0..3
  const int lane = tid & 63;
  const int lr = lane & 15;
  const int kc = lane >> 4;  // 0..3
  const int jb = blockIdx.x * 8;
  const bool has_next = (wih_next != nullptr);

  // ---- Whh preload: fp32 global -> bf16 fragments in VGPRs ----
  bf16x8 warr[2][16];
#pragma unroll
  for (int n = 0; n < 2; ++n) {
    int row = n * 16 + lr;
    int grow = (row >> 3) * H_ + jb + (row & 7);
    const float* wp = whh + (size_t)grow * H_ + wave * 512 + kc * 8;
#pragma unroll
    for (int kk = 0; kk < 16; ++kk) {
      float4 f0 = *(const float4*)(wp + kk * 32);
      float4 f1 = *(const float4*)(wp + kk * 32 + 4);
      bf16x8 w;
      w[0] = f2bf_s(f0.x); w[1] = f2bf_s(f0.y); w[2] = f2bf_s(f0.z); w[3] = f2bf_s(f0.w);
      w[4] = f2bf_s(f1.x); w[5] = f2bf_s(f1.y); w[6] = f2bf_s(f1.z); w[7] = f2bf_s(f1.w);
      warr[n][kk] = w;
    }
  }

  // ---- W_ih,next preload (same row convention), fp32 -> bf16 VGPRs ----
  bf16x8 wnarr[2][16];
  if (has_next) {
#pragma unroll
    for (int n = 0; n < 2; ++n) {
      int row = n * 16 + lr;
      int grow = (row >> 3) * H_ + jb + (row & 7);
      const float* wp = wih_next + (size_t)grow * H_ + wave * 512 + kc * 8;
#pragma unroll
      for (int kk = 0; kk < 16; ++kk) {
        float4 f0 = *(const float4*)(wp + kk * 32);
        float4 f1 = *(const float4*)(wp + kk * 32 + 4);
        bf16x8 w;
        w[0] = f2bf_s(f0.x); w[1] = f2bf_s(f0.y); w[2] = f2bf_s(f0.z); w[3] = f2bf_s(f0.w);
        w[4] = f2bf_s(f1.x); w[5] = f2bf_s(f1.y); w[6] = f2bf_s(f1.z); w[7] = f2bf_s(f1.w);
        wnarr[n][kk] = w;
      }
    }
    if (tid < 32) bbuf[tid] = bias_next[(tid >> 3) * H_ + jb + (tid & 7)];
  }
  __syncthreads();

  const uint4* const H16 = (const uint4*)hfr;
  u64* const hq = (u64*)hfr;

  const int cb = tid & 63;
  const int cp = tid >> 6;
  const int j0 = 2 * cp, j1 = 2 * cp + 1;
  float cst0 = 0.f, cst1 = 0.f;

  // xi_next writeback from red (shared by loop + epilogue)
  auto xi_writeback = [&](int tt) {
    __syncthreads();
#pragma unroll
    for (int j = 0; j < 8; ++j) {
      int e = tid + 256 * j;
      int b = e & 63, r = e >> 6;
      float v = red[0][b][r] + red[1][b][r] + red[2][b][r] + red[3][b][r] + bbuf[r];
      xi_next[((size_t)tt * G4 + (r >> 3) * H_ + jb + (r & 7)) * (size_t)B_ + b] = v;
    }
    __syncthreads();
  };

  for (int t = 0; t < T_; ++t) {
    // ---- xi loads for step t: coalesced, issued BEFORE the flag wait ----
    float xv0[4], xv1[4];
    {
      const float* xp = xi + (size_t)t * G4 * B_ + (size_t)(jb + j0) * B_ + cb;
#pragma unroll
      for (int g = 0; g < 4; ++g) {
        xv0[g] = xp[(size_t)g * H_ * B_];
        xv1[g] = xp[(size_t)g * H_ * B_ + B_];
      }
    }

    f32x4 acc[4][2] = {};
    f32x4 facc[4][2] = {};
    if (t > 0) {
      const unsigned* fp = flg + (size_t)(t - 1) * 256 + wave * 64 + lane;
      while (__hip_atomic_load(fp, __ATOMIC_RELAXED,
                               __HIP_MEMORY_SCOPE_SYSTEM) == 0u)
        __builtin_amdgcn_s_sleep(1);
      asm volatile("" ::: "memory");  // keep cached h loads below the spin

      const size_t base = ((size_t)(t - 1) * 256 + wave * 64 + kc) * 64 + lr;
      uint4 pre[8][4];
#pragma unroll
      for (int d = 0; d < 8; ++d)
#pragma unroll
        for (int m = 0; m < 4; ++m)
          pre[d][m] = H16[base + (size_t)d * 256 + m * 16];
#pragma unroll
      for (int kk = 0; kk < 16; ++kk) {
        const int slot = kk & 7;
        bf16x8 af[4];
#pragma unroll
        for (int m = 0; m < 4; ++m)
          af[m] = frag_from_u4(pre[slot][m]);
        if (kk + 8 < 16) {
#pragma unroll
          for (int m = 0; m < 4; ++m)
            pre[slot][m] = H16[base + (size_t)(kk + 8) * 256 + m * 16];
        }
#pragma unroll
        for (int m = 0; m < 4; ++m) {
          acc[m][0] = __builtin_amdgcn_mfma_f32_16x16x32_bf16(af[m], warr[0][kk], acc[m][0], 0, 0, 0);
          acc[m][1] = __builtin_amdgcn_mfma_f32_16x16x32_bf16(af[m], warr[1][kk], acc[m][1], 0, 0, 0);
        }
        if (has_next) {
#pragma unroll
          for (int m = 0; m < 4; ++m) {
            facc[m][0] = __builtin_amdgcn_mfma_f32_16x16x32_bf16(af[m], wnarr[0][kk], facc[m][0], 0, 0, 0);
            facc[m][1] = __builtin_amdgcn_mfma_f32_16x16x32_bf16(af[m], wnarr[1][kk], facc[m][1], 0, 0, 0);
          }
        }
      }
    }

    // ---- recurrent partials -> LDS; 4-way reduction in cell ----
#pragma unroll
    for (int m = 0; m < 4; ++m)
#pragma unroll
      for (int n = 0; n < 2; ++n)
#pragma unroll
        for (int j = 0; j < 4; ++j)
          red[wave][m * 16 + kc * 4 + j][n * 16 + lr] = acc[m][n][j];
    __syncthreads();

    // ---- LSTM cell ----
    {
      float s00 = red[0][cb][j0]      + red[1][cb][j0]      + red[2][cb][j0]      + red[3][cb][j0];
      float s01 = red[0][cb][8 + j0]  + red[1][cb][8 + j0]  + red[2][cb][8 + j0]  + red[3][cb][8 + j0];
      float s02 = red[0][cb][16 + j0] + red[1][cb][16 + j0] + red[2][cb][16 + j0] + red[3][cb][16 + j0];
      float s03 = red[0][cb][24 + j0] + red[1][cb][24 + j0] + red[2][cb][24 + j0] + red[3][cb][24 + j0];
      float iv = s00 + xv0[0];
      float fv = s01 + xv0[1];
      float gv = s02 + xv0[2];
      float ov = s03 + xv0[3];
      iv = 1.f / (1.f + expf(-iv));
      fv = 1.f / (1.f + expf(-fv));
      gv = tanhf(gv);
      ov = 1.f / (1.f + expf(-ov));
      cst0 = fv * cst0 + iv * gv;
      float hv0 = ov * tanhf(cst0);

      float s10 = red[0][cb][j1]      + red[1][cb][j1]      + red[2][cb][j1]      + red[3][cb][j1];
      float s11 = red[0][cb][8 + j1]  + red[1][cb][8 + j1]  + red[2][cb][8 + j1]  + red[3][cb][8 + j1];
      float s12 = red[0][cb][16 + j1] + red[1][cb][16 + j1] + red[2][cb][16 + j1] + red[3][cb][16 + j1];
      float s13 = red[0][cb][24 + j1] + red[1][cb][24 + j1] + red[2][cb][24 + j1] + red[3][cb][24 + j1];
      float iv1 = s10 + xv1[0];
      float fv1 = s11 + xv1[1];
      float gv1 = s12 + xv1[2];
      float ov1 = s13 + xv1[3];
      iv1 = 1.f / (1.f + expf(-iv1));
      fv1 = 1.f / (1.f + expf(-fv1));
      gv1 = tanhf(gv1);
      ov1 = 1.f / (1.f + expf(-ov1));
      cst1 = fv1 * cst1 + iv1 * gv1;
      float hv1 = ov1 * tanhf(cst1);

      harr[cb][cp] = (unsigned)f2bf(hv0) | ((unsigned)f2bf(hv1) << 16);
      hfar[cb][j0] = hv0;
      hfar[cb][j1] = hv1;
    }
    __syncthreads();

    // ---- wave 0: h write-through stores, then flag (incl. t=15) ----
    if (tid < B_) {
      u64 q0 = (u64)harr[tid][0] | ((u64)harr[tid][1] << 32);
      u64 q1 = (u64)harr[tid][2] | ((u64)harr[tid][3] << 32);
      u64* hp = hq + ((((size_t)t * 256 + blockIdx.x) * 64 + tid) << 1);
      __hip_atomic_store(hp, q0, __ATOMIC_RELAXED, __HIP_MEMORY_SCOPE_SYSTEM);
      __hip_atomic_store(hp + 1, q1, __ATOMIC_RELAXED, __HIP_MEMORY_SCOPE_SYSTEM);
      if (out32 != nullptr) {
        float* op = out32 + ((size_t)tid * T_ + t) * H_ + jb;
        float4 v0, v1;
        v0.x = hfar[tid][0]; v0.y = hfar[tid][1]; v0.z = hfar[tid][2]; v0.w = hfar[tid][3];
        v1.x = hfar[tid][4]; v1.y = hfar[tid][5]; v1.z = hfar[tid][6]; v1.w = hfar[tid][7];
        *(float4*)op = v0;
        *(float4*)(op + 4) = v1;
      }
    }
    if (tid == 0) {
      asm volatile("s_waitcnt vmcnt(0)" ::: "memory");  // h at coherence point
      __hip_atomic_store(flg + (size_t)t * 256 + blockIdx.x, 1u,
                         __ATOMIC_RELAXED, __HIP_MEMORY_SCOPE_SYSTEM);
    }

    // ---- OFF critical path: xi_next(t-1) reduce + store ----
    if (has_next && t > 0) {
      __syncthreads();
#pragma unroll
      for (int m = 0; m < 4; ++m)
#pragma unroll
        for (int n = 0; n < 2; ++n)
#pragma unroll
          for (int j = 0; j < 4; ++j)
            red[wave][m * 16 + kc * 4 + j][n * 16 + lr] = facc[m][n][j];
      xi_writeback(t - 1);
    }
  }

  // ---- epilogue: xi_next(15) via flag[15] ----
  if (has_next) {
    const unsigned* fp = flg + (size_t)15 * 256 + wave * 64 + lane;
    while (__hip_atomic_load(fp, __ATOMIC_RELAXED,
                             __HIP_MEMORY_SCOPE_SYSTEM) == 0u)
      __builtin_amdgcn_s_sleep(1);
    asm volatile("" ::: "memory");

    f32x4 facc[4][2] = {};
    const size_t base = ((size_t)15 * 256 + wave * 64 + kc) * 64 + lr;
    uint4 pre[8][4];
#pragma unroll
    for (int d = 0; d < 8; ++d)
#pragma unroll
      for (int m = 0; m < 4; ++m)
        pre[d][m] = H16[base + (size_t)d * 256 + m * 16];
#pragma unroll
    for (int kk = 0; kk < 16; ++kk) {
      const int slot = kk & 7;
      bf16x8 af[4];
#pragma unroll
      for (int m = 0; m < 4; ++m)
        af[m] = frag_from_u4(pre[slot][m]);
      if (kk + 8 < 16) {
#pragma unroll
        for (int m = 0; m < 4; ++m)
          pre[slot][m] = H16[base + (size_t)(kk + 8) * 256 + m * 16];
      }
#pragma unroll
      for (int m = 0; m < 4; ++m) {
        facc[m][0] = __builtin_amdgcn_mfma_f32_16x16x32_bf16(af[m], wnarr[0][kk], facc[m][0], 0, 0, 0);
        facc[m][1] = __builtin_amdgcn_mfma_f32_16x16x32_bf16(af[m], wnarr[1][kk], facc[m][1], 0, 0, 0);
      }
    }
    __syncthreads();
#pragma unroll
    for (int m = 0; m < 4; ++m)
#pragma unroll
      for (int n = 0; n < 2; ++n)
#pragma unroll
        for (int j = 0; j < 4; ++j)
          red[wave][m * 16 + kc * 4 + j][n * 16 + lr] = facc[m][n][j];
    xi_writeback(15);
  }
}

extern "C" void kernel_launch(void* const* d_in, const int* in_sizes, int n_in,
                              void* d_out, int out_size, void* d_ws, size_t ws_size,
                              hipStream_t stream) {
  const float* x    = (const float*)d_in[0];
  const float* wih0 = (const float*)d_in[1];
  const float* whh0 = (const float*)d_in[2];
  const float* bih0 = (const float*)d_in[3];
  const float* bhh0 = (const float*)d_in[4];
  const float* wihr = (const float*)d_in[5];
  const float* whhr = (const float*)d_in[6];
  const float* bihr = (const float*)d_in[7];
  const float* bhhr = (const float*)d_in[8];
  float* out = (float*)d_out;

  char* ws = (char*)d_ws;
  size_t off = 0;
  auto alloc = [&](size_t bytes) -> void* {
    void* p = ws + off;
    off += (bytes + 255) & ~(size_t)255;
    return p;
  };
  u16*      wih_b = (u16*)alloc((size_t)G4 * D0 * 2);   // layer 0 only
  float*    bias  = (float*)alloc(4ull * G4 * 4);
  float*    xiA   = (float*)alloc((size_t)T_ * B_ * G4 * 4);
  float*    xiB   = (float*)alloc((size_t)T_ * B_ * G4 * 4);
  u16*      Ax    = (u16*)alloc((size_t)T_ * B_ * D0 * 2);
  u16*      bufA  = (u16*)alloc((size_t)T_ * B_ * H_ * 2);
  u16*      bufB  = (u16*)alloc((size_t)T_ * B_ * H_ * 2);
  unsigned* flags = (unsigned*)alloc(4ull * 16 * 256 * sizeof(unsigned));

  auto cgrid = [](int n8) { int g = (n8 + 255) / 256; return g > 8192 ? 8192 : g; };

  hipMemsetAsync(flags, 0, 4ull * 16 * 256 * sizeof(unsigned), stream);

  int n8 = (G4 * D0) / 8;
  k_f32_to_bf16<<<cgrid(n8), 256, 0, stream>>>(wih0, wih_b, n8);

  k_bias<<<(4 * G4 + 255) / 256, 256, 0, stream>>>(bih0, bhh0, bihr, bhhr, bias);
  k_stage_x<<<(T_ * (D0 / 8) * B_ + 255) / 256, 256, 0, stream>>>(x, (uint4*)Ax);

  // layer 0 input projection (the only standalone GEMM)
  {
    dim3 g(G4 / 128, (T_ * B_) / 128);
    k_gemm_xi<<<g, 256, 0, stream>>>(Ax, wih_b, bias, xiA, D0, D0 / 8);
  }

  for (int l = 0; l < 4; ++l) {
    const float* whh_l = (l == 0) ? whh0 : (whhr + (size_t)(l - 1) * G4 * H_);
    u16* hbuf = (l & 1) ? bufB : bufA;
    float* o32 = (l == 3) ? out : nullptr;
    float* xi_in  = (l & 1) ? xiB : xiA;
    float* xi_out = (l & 1) ? xiA : xiB;
    const float* wih_next = (l < 3) ? (wihr + (size_t)l * G4 * H_) : nullptr;
    const float* bias_next = bias + (size_t)((l + 1) & 3) * G4;

    k_lstm_seq<<<NB, 256, 0, stream>>>(whh_l, xi_in, hbuf, o32,
                                       flags + (size_t)l * 16 * 256,
                                       wih_next, bias_next, xi_out);
  }
}

// Round 13
// 641.798 us; speedup vs baseline: 1.1039x; 1.1011x over previous
//
#include <hip/hip_runtime.h>
#include <stdint.h>

#define B_ 64
#define T_ 16
#define D0 1024
#define H_ 2048
#define G4 8192  // 4*H
#define NB 256   // persistent blocks (one per CU)

typedef unsigned short u16;
typedef unsigned long long u64;
typedef __attribute__((ext_vector_type(4))) float f32x4;
typedef __attribute__((ext_vector_type(8))) short bf16x8;

__device__ __forceinline__ u16 f2bf(float f) {
  unsigned int u = __builtin_bit_cast(unsigned int, f);
  unsigned int r = (u + 0x7FFFu + ((u >> 16) & 1u)) >> 16;
  return (u16)r;
}
__device__ __forceinline__ short f2bf_s(float f) { return (short)f2bf(f); }

__device__ __forceinline__ void gld_lds16(const void* g, void* l) {
  __builtin_amdgcn_global_load_lds(
      (const __attribute__((address_space(1))) void*)g,
      (__attribute__((address_space(3))) void*)l, 16, 0, 0);
}

__device__ __forceinline__ bf16x8 frag_from_u4(uint4 q) {
  return __builtin_bit_cast(bf16x8, q);
}

// ---------------- fp32 -> bf16 bulk conversion (RTN) ----------------
__global__ __launch_bounds__(256) void k_f32_to_bf16(
    const float* __restrict__ src, u16* __restrict__ dst, int n8) {
  int i = blockIdx.x * 256 + threadIdx.x;
  int stride = gridDim.x * 256;
  const float4* s = (const float4*)src;
  uint4* d = (uint4*)dst;
  for (; i < n8; i += stride) {
    float4 a = s[2 * i], b = s[2 * i + 1];
    uint4 o;
    o.x = f2bf(a.x) | ((unsigned)f2bf(a.y) << 16);
    o.y = f2bf(a.z) | ((unsigned)f2bf(a.w) << 16);
    o.z = f2bf(b.x) | ((unsigned)f2bf(b.y) << 16);
    o.w = f2bf(b.z) | ((unsigned)f2bf(b.w) << 16);
    d[i] = o;
  }
}

// ---------------- combined bias: b_ih + b_hh, 4 layers ----------------
__global__ __launch_bounds__(256) void k_bias(
    const float* __restrict__ bih0, const float* __restrict__ bhh0,
    const float* __restrict__ bihr, const float* __restrict__ bhhr,
    float* __restrict__ bias) {
  int i = blockIdx.x * 256 + threadIdx.x;
  if (i >= 4 * G4) return;
  int l = i >> 13, j = i & (G4 - 1);
  float a = (l == 0) ? bih0[j] : bihr[(l - 1) * G4 + j];
  float b = (l == 0) ? bhh0[j] : bhhr[(l - 1) * G4 + j];
  bias[i] = a + b;
}

// ---- stage x [B,T,D0] fp32 -> chunk layout: Ax16[(t*128 + k/8)*64 + b] ----
__global__ __launch_bounds__(256) void k_stage_x(
    const float* __restrict__ x, uint4* __restrict__ A16) {
  int i = blockIdx.x * 256 + threadIdx.x;
  if (i >= T_ * (D0 / 8) * B_) return;
  int chunk = i & 127;
  int r = i >> 7;
  int b = r & (B_ - 1), t = r >> 6;
  const float4* s = (const float4*)(x + ((size_t)(b * T_ + t)) * D0 + chunk * 8);
  float4 a0 = s[0], a1 = s[1];
  uint4 o;
  o.x = f2bf(a0.x) | ((unsigned)f2bf(a0.y) << 16);
  o.y = f2bf(a0.z) | ((unsigned)f2bf(a0.w) << 16);
  o.z = f2bf(a1.x) | ((unsigned)f2bf(a1.y) << 16);
  o.w = f2bf(a1.z) | ((unsigned)f2bf(a1.w) << 16);
  A16[((size_t)t * 128 + chunk) * 64 + b] = o;
}

// ---------------- input-projection GEMM (layer 0 only) ----------------
__global__ __launch_bounds__(256) void k_gemm_xi(
    const u16* __restrict__ A, const u16* __restrict__ W,
    const float* __restrict__ bias, float* __restrict__ C, int K, int CH) {
  __shared__ __align__(16) u16 sA[128 * 32];
  __shared__ __align__(16) u16 sB[128 * 32];
  const int tid = threadIdx.x;
  const int wave = tid >> 6;
  const int lane = tid & 63;
  const int m0 = blockIdx.y * 128;
  const int n0 = blockIdx.x * 128;
  const int wr = wave >> 1, wc = wave & 1;
  const int lr = lane & 15;
  const int kc = (lane >> 4) * 8;
  const int rowA = tid >> 2, colk = (tid & 3) * 8;

  f32x4 acc[4][4] = {};

  for (int k0 = 0; k0 < K; k0 += 32) {
#pragma unroll
    for (int iss = 0; iss < 2; ++iss) {
      int row = m0 + iss * 64 + rowA;
      int tt = row >> 6, bb = row & 63;
      int chunk = (k0 + colk) >> 3;
      gld_lds16(A + ((((size_t)tt * CH + chunk) * 64 + bb) << 3),
                sA + (iss * 64 + wave * 16) * 32);
      gld_lds16(W + (size_t)(n0 + iss * 64 + rowA) * K + k0 + colk,
                sB + (iss * 64 + wave * 16) * 32);
    }
    __syncthreads();
    bf16x8 a[4], b[4];
#pragma unroll
    for (int m = 0; m < 4; ++m)
      a[m] = *(const bf16x8*)&sA[(wr * 64 + m * 16 + lr) * 32 + kc];
#pragma unroll
    for (int n = 0; n < 4; ++n)
      b[n] = *(const bf16x8*)&sB[(wc * 64 + n * 16 + lr) * 32 + kc];
#pragma unroll
    for (int m = 0; m < 4; ++m)
#pragma unroll
      for (int n = 0; n < 4; ++n)
        acc[m][n] = __builtin_amdgcn_mfma_f32_16x16x32_bf16(a[m], b[n], acc[m][n], 0, 0, 0);
    __syncthreads();
  }

#pragma unroll
  for (int n = 0; n < 4; ++n) {
    int col = n0 + wc * 64 + n * 16 + lr;
    float bv = bias[col];
#pragma unroll
    for (int m = 0; m < 4; ++m) {
      int row0 = m0 + wr * 64 + m * 16 + ((lane >> 4) << 2);
      int t = row0 >> 6, b0 = row0 & 63;
      float4 v;
      v.x = acc[m][n][0] + bv;
      v.y = acc[m][n][1] + bv;
      v.z = acc[m][n][2] + bv;
      v.w = acc[m][n][3] + bv;
      *(float4*)&C[((size_t)t * G4 + col) * B_ + b0] = v;
    }
  }
}

// ---------------- persistent per-layer recurrent kernel ----------------
// R10 validated structure (depth-2 h prefetch). Critical-path changes:
// (1) per-thread direct write-through h stores from the cell (no LDS
//     staging, no wave-0-only store phase, one less barrier);
// (2) per-wave vmcnt(0) drain + single barrier before the flag store;
// (3) facc MFMAs issued before acc within each kk (chain finishes earlier).
__global__ __launch_bounds__(256, 1) void k_lstm_seq(
    const float* __restrict__ whh,      // [8192][2048] fp32
    const float* __restrict__ xi,       // [T][G4][B] fp32 (bias folded)
    u16* __restrict__ hfr,              // [T][256][64] x 16B chunk layout
    float* __restrict__ out32,          // null, or [B][T][2048] fp32
    unsigned* __restrict__ flg,         // [16][256] one-shot flags, zeroed
    const float* __restrict__ wih_next, // null, or [8192][2048] fp32
    const float* __restrict__ bias_next,// [G4]
    float* __restrict__ xi_next) {      // [T][G4][B] fp32 out
  __builtin_amdgcn_fence(__ATOMIC_ACQUIRE, "agent");

  __shared__ float red[4][64][33];
  __shared__ float bbuf[32];

  const int tid = threadIdx.x;
  const int wave = tid >> 6;  // K-slice index 0..3
  const int lane = tid & 63;
  const int lr = lane & 15;
  const int kc = lane >> 4;  // 0..3
  const int jb = blockIdx.x * 8;
  const bool has_next = (wih_next != nullptr);

  // ---- Whh preload: fp32 global -> bf16 fragments in VGPRs ----
  bf16x8 warr[2][16];
#pragma unroll
  for (int n = 0; n < 2; ++n) {
    int row = n * 16 + lr;
    int grow = (row >> 3) * H_ + jb + (row & 7);
    const float* wp = whh + (size_t)grow * H_ + wave * 512 + kc * 8;
#pragma unroll
    for (int kk = 0; kk < 16; ++kk) {
      float4 f0 = *(const float4*)(wp + kk * 32);
      float4 f1 = *(const float4*)(wp + kk * 32 + 4);
      bf16x8 w;
      w[0] = f2bf_s(f0.x); w[1] = f2bf_s(f0.y); w[2] = f2bf_s(f0.z); w[3] = f2bf_s(f0.w);
      w[4] = f2bf_s(f1.x); w[5] = f2bf_s(f1.y); w[6] = f2bf_s(f1.z); w[7] = f2bf_s(f1.w);
      warr[n][kk] = w;
    }
  }

  // ---- W_ih,next preload (same row convention), fp32 -> bf16 VGPRs ----
  bf16x8 wnarr[2][16];
  if (has_next) {
#pragma unroll
    for (int n = 0; n < 2; ++n) {
      int row = n * 16 + lr;
      int grow = (row >> 3) * H_ + jb + (row & 7);
      const float* wp = wih_next + (size_t)grow * H_ + wave * 512 + kc * 8;
#pragma unroll
      for (int kk = 0; kk < 16; ++kk) {
        float4 f0 = *(const float4*)(wp + kk * 32);
        float4 f1 = *(const float4*)(wp + kk * 32 + 4);
        bf16x8 w;
        w[0] = f2bf_s(f0.x); w[1] = f2bf_s(f0.y); w[2] = f2bf_s(f0.z); w[3] = f2bf_s(f0.w);
        w[4] = f2bf_s(f1.x); w[5] = f2bf_s(f1.y); w[6] = f2bf_s(f1.z); w[7] = f2bf_s(f1.w);
        wnarr[n][kk] = w;
      }
    }
    if (tid < 32) bbuf[tid] = bias_next[(tid >> 3) * H_ + jb + (tid & 7)];
  }
  __syncthreads();

  const uint4* const H16 = (const uint4*)hfr;
  unsigned* const h32 = (unsigned*)hfr;

  const int cb = tid & 63;
  const int cp = tid >> 6;
  const int j0 = 2 * cp, j1 = 2 * cp + 1;
  float cst0 = 0.f, cst1 = 0.f;

  // xi_next writeback from red (shared by loop + epilogue)
  auto xi_writeback = [&](int tt) {
    __syncthreads();
#pragma unroll
    for (int j = 0; j < 8; ++j) {
      int e = tid + 256 * j;
      int b = e & 63, r = e >> 6;
      float v = red[0][b][r] + red[1][b][r] + red[2][b][r] + red[3][b][r] + bbuf[r];
      xi_next[((size_t)tt * G4 + (r >> 3) * H_ + jb + (r & 7)) * (size_t)B_ + b] = v;
    }
    __syncthreads();
  };

  for (int t = 0; t < T_; ++t) {
    // ---- xi loads for step t: coalesced, issued BEFORE the flag wait ----
    float xv0[4], xv1[4];
    {
      const float* xp = xi + (size_t)t * G4 * B_ + (size_t)(jb + j0) * B_ + cb;
#pragma unroll
      for (int g = 0; g < 4; ++g) {
        xv0[g] = xp[(size_t)g * H_ * B_];
        xv1[g] = xp[(size_t)g * H_ * B_ + B_];
      }
    }

    f32x4 acc[4][2] = {};
    f32x4 facc[4][2] = {};
    if (t > 0) {
      const unsigned* fp = flg + (size_t)(t - 1) * 256 + wave * 64 + lane;
      while (__hip_atomic_load(fp, __ATOMIC_RELAXED,
                               __HIP_MEMORY_SCOPE_SYSTEM) == 0u)
        __builtin_amdgcn_s_sleep(1);
      asm volatile("" ::: "memory");  // keep cached h loads below the spin

      const size_t base = ((size_t)(t - 1) * 256 + wave * 64 + kc) * 64 + lr;
      uint4 pre[2][4];
#pragma unroll
      for (int d = 0; d < 2; ++d)
#pragma unroll
        for (int m = 0; m < 4; ++m)
          pre[d][m] = H16[base + (size_t)d * 256 + m * 16];
#pragma unroll
      for (int kk = 0; kk < 16; ++kk) {
        const int slot = kk & 1;
        bf16x8 af[4];
#pragma unroll
        for (int m = 0; m < 4; ++m)
          af[m] = frag_from_u4(pre[slot][m]);
        if (kk + 2 < 16) {
#pragma unroll
          for (int m = 0; m < 4; ++m)
            pre[slot][m] = H16[base + (size_t)(kk + 2) * 256 + m * 16];
        }
        // facc first: off-chain results drain in the pipe while the
        // chain-critical acc path proceeds to the reduction.
        if (has_next) {
#pragma unroll
          for (int m = 0; m < 4; ++m) {
            facc[m][0] = __builtin_amdgcn_mfma_f32_16x16x32_bf16(af[m], wnarr[0][kk], facc[m][0], 0, 0, 0);
            facc[m][1] = __builtin_amdgcn_mfma_f32_16x16x32_bf16(af[m], wnarr[1][kk], facc[m][1], 0, 0, 0);
          }
        }
#pragma unroll
        for (int m = 0; m < 4; ++m) {
          acc[m][0] = __builtin_amdgcn_mfma_f32_16x16x32_bf16(af[m], warr[0][kk], acc[m][0], 0, 0, 0);
          acc[m][1] = __builtin_amdgcn_mfma_f32_16x16x32_bf16(af[m], warr[1][kk], acc[m][1], 0, 0, 0);
        }
      }
    }

    // ---- recurrent partials -> LDS; 4-way reduction in cell ----
#pragma unroll
    for (int m = 0; m < 4; ++m)
#pragma unroll
      for (int n = 0; n < 2; ++n)
#pragma unroll
        for (int j = 0; j < 4; ++j)
          red[wave][m * 16 + kc * 4 + j][n * 16 + lr] = acc[m][n][j];
    __syncthreads();

    // ---- LSTM cell + direct per-thread h / out32 stores ----
    {
      float s00 = red[0][cb][j0]      + red[1][cb][j0]      + red[2][cb][j0]      + red[3][cb][j0];
      float s01 = red[0][cb][8 + j0]  + red[1][cb][8 + j0]  + red[2][cb][8 + j0]  + red[3][cb][8 + j0];
      float s02 = red[0][cb][16 + j0] + red[1][cb][16 + j0] + red[2][cb][16 + j0] + red[3][cb][16 + j0];
      float s03 = red[0][cb][24 + j0] + red[1][cb][24 + j0] + red[2][cb][24 + j0] + red[3][cb][24 + j0];
      float iv = s00 + xv0[0];
      float fv = s01 + xv0[1];
      float gv = s02 + xv0[2];
      float ov = s03 + xv0[3];
      iv = 1.f / (1.f + expf(-iv));
      fv = 1.f / (1.f + expf(-fv));
      gv = tanhf(gv);
      ov = 1.f / (1.f + expf(-ov));
      cst0 = fv * cst0 + iv * gv;
      float hv0 = ov * tanhf(cst0);

      float s10 = red[0][cb][j1]      + red[1][cb][j1]      + red[2][cb][j1]      + red[3][cb][j1];
      float s11 = red[0][cb][8 + j1]  + red[1][cb][8 + j1]  + red[2][cb][8 + j1]  + red[3][cb][8 + j1];
      float s12 = red[0][cb][16 + j1] + red[1][cb][16 + j1] + red[2][cb][16 + j1] + red[3][cb][16 + j1];
      float s13 = red[0][cb][24 + j1] + red[1][cb][24 + j1] + red[2][cb][24 + j1] + red[3][cb][24 + j1];
      float iv1 = s10 + xv1[0];
      float fv1 = s11 + xv1[1];
      float gv1 = s12 + xv1[2];
      float ov1 = s13 + xv1[3];
      iv1 = 1.f / (1.f + expf(-iv1));
      fv1 = 1.f / (1.f + expf(-fv1));
      gv1 = tanhf(gv1);
      ov1 = 1.f / (1.f + expf(-ov1));
      cst1 = fv1 * cst1 + iv1 * gv1;
      float hv1 = ov1 * tanhf(cst1);

      unsigned hpack = (unsigned)f2bf(hv0) | ((unsigned)f2bf(hv1) << 16);
      unsigned* hp = h32 + ((((size_t)t * 256 + blockIdx.x) * 64 + cb) << 2) + cp;
      __hip_atomic_store(hp, hpack, __ATOMIC_RELAXED, __HIP_MEMORY_SCOPE_SYSTEM);
      if (out32 != nullptr) {
        float2 o2 = {hv0, hv1};
        *(float2*)(out32 + ((size_t)cb * T_ + t) * H_ + jb + j0) = o2;
      }
    }

    // ---- drain each wave's stores, then one barrier, then the flag ----
    asm volatile("s_waitcnt vmcnt(0)" ::: "memory");
    __syncthreads();
    if (tid == 0)
      __hip_atomic_store(flg + (size_t)t * 256 + blockIdx.x, 1u,
                         __ATOMIC_RELAXED, __HIP_MEMORY_SCOPE_SYSTEM);

    // ---- OFF critical path: xi_next(t-1) reduce + store ----
    if (has_next && t > 0) {
#pragma unroll
      for (int m = 0; m < 4; ++m)
#pragma unroll
        for (int n = 0; n < 2; ++n)
#pragma unroll
          for (int j = 0; j < 4; ++j)
            red[wave][m * 16 + kc * 4 + j][n * 16 + lr] = facc[m][n][j];
      xi_writeback(t - 1);
    }
  }

  // ---- epilogue: xi_next(15) via flag[15] ----
  if (has_next) {
    const unsigned* fp = flg + (size_t)15 * 256 + wave * 64 + lane;
    while (__hip_atomic_load(fp, __ATOMIC_RELAXED,
                             __HIP_MEMORY_SCOPE_SYSTEM) == 0u)
      __builtin_amdgcn_s_sleep(1);
    asm volatile("" ::: "memory");

    f32x4 facc[4][2] = {};
    const size_t base = ((size_t)15 * 256 + wave * 64 + kc) * 64 + lr;
    uint4 pre[2][4];
#pragma unroll
    for (int d = 0; d < 2; ++d)
#pragma unroll
      for (int m = 0; m < 4; ++m)
        pre[d][m] = H16[base + (size_t)d * 256 + m * 16];
#pragma unroll
    for (int kk = 0; kk < 16; ++kk) {
      const int slot = kk & 1;
      bf16x8 af[4];
#pragma unroll
      for (int m = 0; m < 4; ++m)
        af[m] = frag_from_u4(pre[slot][m]);
      if (kk + 2 < 16) {
#pragma unroll
        for (int m = 0; m < 4; ++m)
          pre[slot][m] = H16[base + (size_t)(kk + 2) * 256 + m * 16];
      }
#pragma unroll
      for (int m = 0; m < 4; ++m) {
        facc[m][0] = __builtin_amdgcn_mfma_f32_16x16x32_bf16(af[m], wnarr[0][kk], facc[m][0], 0, 0, 0);
        facc[m][1] = __builtin_amdgcn_mfma_f32_16x16x32_bf16(af[m], wnarr[1][kk], facc[m][1], 0, 0, 0);
      }
    }
    __syncthreads();
#pragma unroll
    for (int m = 0; m < 4; ++m)
#pragma unroll
      for (int n = 0; n < 2; ++n)
#pragma unroll
        for (int j = 0; j < 4; ++j)
          red[wave][m * 16 + kc * 4 + j][n * 16 + lr] = facc[m][n][j];
    xi_writeback(15);
  }
}

extern "C" void kernel_launch(void* const* d_in, const int* in_sizes, int n_in,
                              void* d_out, int out_size, void* d_ws, size_t ws_size,
                              hipStream_t stream) {
  const float* x    = (const float*)d_in[0];
  const float* wih0 = (const float*)d_in[1];
  const float* whh0 = (const float*)d_in[2];
  const float* bih0 = (const float*)d_in[3];
  const float* bhh0 = (const float*)d_in[4];
  const float* wihr = (const float*)d_in[5];
  const float* whhr = (const float*)d_in[6];
  const float* bihr = (const float*)d_in[7];
  const float* bhhr = (const float*)d_in[8];
  float* out = (float*)d_out;

  char* ws = (char*)d_ws;
  size_t off = 0;
  auto alloc = [&](size_t bytes) -> void* {
    void* p = ws + off;
    off += (bytes + 255) & ~(size_t)255;
    return p;
  };
  u16*      wih_b = (u16*)alloc((size_t)G4 * D0 * 2);   // layer 0 only
  float*    bias  = (float*)alloc(4ull * G4 * 4);
  float*    xiA   = (float*)alloc((size_t)T_ * B_ * G4 * 4);
  float*    xiB   = (float*)alloc((size_t)T_ * B_ * G4 * 4);
  u16*      Ax    = (u16*)alloc((size_t)T_ * B_ * D0 * 2);
  u16*      bufA  = (u16*)alloc((size_t)T_ * B_ * H_ * 2);
  u16*      bufB  = (u16*)alloc((size_t)T_ * B_ * H_ * 2);
  unsigned* flags = (unsigned*)alloc(4ull * 16 * 256 * sizeof(unsigned));

  auto cgrid = [](int n8) { int g = (n8 + 255) / 256; return g > 8192 ? 8192 : g; };

  hipMemsetAsync(flags, 0, 4ull * 16 * 256 * sizeof(unsigned), stream);

  int n8 = (G4 * D0) / 8;
  k_f32_to_bf16<<<cgrid(n8), 256, 0, stream>>>(wih0, wih_b, n8);

  k_bias<<<(4 * G4 + 255) / 256, 256, 0, stream>>>(bih0, bhh0, bihr, bhhr, bias);
  k_stage_x<<<(T_ * (D0 / 8) * B_ + 255) / 256, 256, 0, stream>>>(x, (uint4*)Ax);

  // layer 0 input projection (the only standalone GEMM)
  {
    dim3 g(G4 / 128, (T_ * B_) / 128);
    k_gemm_xi<<<g, 256, 0, stream>>>(Ax, wih_b, bias, xiA, D0, D0 / 8);
  }

  for (int l = 0; l < 4; ++l) {
    const float* whh_l = (l == 0) ? whh0 : (whhr + (size_t)(l - 1) * G4 * H_);
    u16* hbuf = (l & 1) ? bufB : bufA;
    float* o32 = (l == 3) ? out : nullptr;
    float* xi_in  = (l & 1) ? xiB : xiA;
    float* xi_out = (l & 1) ? xiA : xiB;
    const float* wih_next = (l < 3) ? (wihr + (size_t)l * G4 * H_) : nullptr;
    const float* bias_next = bias + (size_t)((l + 1) & 3) * G4;

    k_lstm_seq<<<NB, 256, 0, stream>>>(whh_l, xi_in, hbuf, o32,
                                       flags + (size_t)l * 16 * 256,
                                       wih_next, bias_next, xi_out);
  }
}

// Round 14
// 628.887 us; speedup vs baseline: 1.1265x; 1.0205x over previous
//
#include <hip/hip_runtime.h>
#include <stdint.h>

#define B_ 64
#define T_ 16
#define D0 1024
#define H_ 2048
#define G4 8192  // 4*H
#define NB 256   // persistent blocks (one per CU)

typedef unsigned short u16;
typedef unsigned long long u64;
typedef __attribute__((ext_vector_type(4))) float f32x4;
typedef __attribute__((ext_vector_type(8))) short bf16x8;

__device__ __forceinline__ u16 f2bf(float f) {
  unsigned int u = __builtin_bit_cast(unsigned int, f);
  unsigned int r = (u + 0x7FFFu + ((u >> 16) & 1u)) >> 16;
  return (u16)r;
}
__device__ __forceinline__ short f2bf_s(float f) { return (short)f2bf(f); }

__device__ __forceinline__ void gld_lds16(const void* g, void* l) {
  __builtin_amdgcn_global_load_lds(
      (const __attribute__((address_space(1))) void*)g,
      (__attribute__((address_space(3))) void*)l, 16, 0, 0);
}

__device__ __forceinline__ bf16x8 frag_from_u4(uint4 q) {
  return __builtin_bit_cast(bf16x8, q);
}

// ---------------- fp32 -> bf16 bulk conversion (RTN) ----------------
__global__ __launch_bounds__(256) void k_f32_to_bf16(
    const float* __restrict__ src, u16* __restrict__ dst, int n8) {
  int i = blockIdx.x * 256 + threadIdx.x;
  int stride = gridDim.x * 256;
  const float4* s = (const float4*)src;
  uint4* d = (uint4*)dst;
  for (; i < n8; i += stride) {
    float4 a = s[2 * i], b = s[2 * i + 1];
    uint4 o;
    o.x = f2bf(a.x) | ((unsigned)f2bf(a.y) << 16);
    o.y = f2bf(a.z) | ((unsigned)f2bf(a.w) << 16);
    o.z = f2bf(b.x) | ((unsigned)f2bf(b.y) << 16);
    o.w = f2bf(b.z) | ((unsigned)f2bf(b.w) << 16);
    d[i] = o;
  }
}

// ---------------- combined bias: b_ih + b_hh, 4 layers ----------------
__global__ __launch_bounds__(256) void k_bias(
    const float* __restrict__ bih0, const float* __restrict__ bhh0,
    const float* __restrict__ bihr, const float* __restrict__ bhhr,
    float* __restrict__ bias) {
  int i = blockIdx.x * 256 + threadIdx.x;
  if (i >= 4 * G4) return;
  int l = i >> 13, j = i & (G4 - 1);
  float a = (l == 0) ? bih0[j] : bihr[(l - 1) * G4 + j];
  float b = (l == 0) ? bhh0[j] : bhhr[(l - 1) * G4 + j];
  bias[i] = a + b;
}

// ---- stage x [B,T,D0] fp32 -> chunk layout: Ax16[(t*128 + k/8)*64 + b] ----
__global__ __launch_bounds__(256) void k_stage_x(
    const float* __restrict__ x, uint4* __restrict__ A16) {
  int i = blockIdx.x * 256 + threadIdx.x;
  if (i >= T_ * (D0 / 8) * B_) return;
  int chunk = i & 127;
  int r = i >> 7;
  int b = r & (B_ - 1), t = r >> 6;
  const float4* s = (const float4*)(x + ((size_t)(b * T_ + t)) * D0 + chunk * 8);
  float4 a0 = s[0], a1 = s[1];
  uint4 o;
  o.x = f2bf(a0.x) | ((unsigned)f2bf(a0.y) << 16);
  o.y = f2bf(a0.z) | ((unsigned)f2bf(a0.w) << 16);
  o.z = f2bf(a1.x) | ((unsigned)f2bf(a1.y) << 16);
  o.w = f2bf(a1.z) | ((unsigned)f2bf(a1.w) << 16);
  A16[((size_t)t * 128 + chunk) * 64 + b] = o;
}

// ---------------- input-projection GEMM (layer 0 only) ----------------
__global__ __launch_bounds__(256) void k_gemm_xi(
    const u16* __restrict__ A, const u16* __restrict__ W,
    const float* __restrict__ bias, float* __restrict__ C, int K, int CH) {
  __shared__ __align__(16) u16 sA[128 * 32];
  __shared__ __align__(16) u16 sB[128 * 32];
  const int tid = threadIdx.x;
  const int wave = tid >> 6;
  const int lane = tid & 63;
  const int m0 = blockIdx.y * 128;
  const int n0 = blockIdx.x * 128;
  const int wr = wave >> 1, wc = wave & 1;
  const int lr = lane & 15;
  const int kc = (lane >> 4) * 8;
  const int rowA = tid >> 2, colk = (tid & 3) * 8;

  f32x4 acc[4][4] = {};

  for (int k0 = 0; k0 < K; k0 += 32) {
#pragma unroll
    for (int iss = 0; iss < 2; ++iss) {
      int row = m0 + iss * 64 + rowA;
      int tt = row >> 6, bb = row & 63;
      int chunk = (k0 + colk) >> 3;
      gld_lds16(A + ((((size_t)tt * CH + chunk) * 64 + bb) << 3),
                sA + (iss * 64 + wave * 16) * 32);
      gld_lds16(W + (size_t)(n0 + iss * 64 + rowA) * K + k0 + colk,
                sB + (iss * 64 + wave * 16) * 32);
    }
    __syncthreads();
    bf16x8 a[4], b[4];
#pragma unroll
    for (int m = 0; m < 4; ++m)
      a[m] = *(const bf16x8*)&sA[(wr * 64 + m * 16 + lr) * 32 + kc];
#pragma unroll
    for (int n = 0; n < 4; ++n)
      b[n] = *(const bf16x8*)&sB[(wc * 64 + n * 16 + lr) * 32 + kc];
#pragma unroll
    for (int m = 0; m < 4; ++m)
#pragma unroll
      for (int n = 0; n < 4; ++n)
        acc[m][n] = __builtin_amdgcn_mfma_f32_16x16x32_bf16(a[m], b[n], acc[m][n], 0, 0, 0);
    __syncthreads();
  }

#pragma unroll
  for (int n = 0; n < 4; ++n) {
    int col = n0 + wc * 64 + n * 16 + lr;
    float bv = bias[col];
#pragma unroll
    for (int m = 0; m < 4; ++m) {
      int row0 = m0 + wr * 64 + m * 16 + ((lane >> 4) << 2);
      int t = row0 >> 6, b0 = row0 & 63;
      float4 v;
      v.x = acc[m][n][0] + bv;
      v.y = acc[m][n][1] + bv;
      v.z = acc[m][n][2] + bv;
      v.w = acc[m][n][3] + bv;
      *(float4*)&C[((size_t)t * G4 + col) * B_ + b0] = v;
    }
  }
}

// ---------------- persistent per-layer recurrent kernel ----------------
// R10 champion structure (628 us): VGPR-resident Whh + W_ih,next; fused
// next-layer xi (register-only, same h fragments); per-block one-shot
// flags (relaxed system stores); write-through h stores; cached h reads
// with depth-2 prefetch; xi_next writeback off the critical path.
__global__ __launch_bounds__(256, 1) void k_lstm_seq(
    const float* __restrict__ whh,      // [8192][2048] fp32
    const float* __restrict__ xi,       // [T][G4][B] fp32 (bias folded)
    u16* __restrict__ hfr,              // [T][256][64] x 16B chunk layout
    float* __restrict__ out32,          // null, or [B][T][2048] fp32
    unsigned* __restrict__ flg,         // [16][256] one-shot flags, zeroed
    const float* __restrict__ wih_next, // null, or [8192][2048] fp32
    const float* __restrict__ bias_next,// [G4]
    float* __restrict__ xi_next) {      // [T][G4][B] fp32 out
  __builtin_amdgcn_fence(__ATOMIC_ACQUIRE, "agent");

  __shared__ float red[4][64][33];
  __shared__ unsigned harr[64][4];
  __shared__ float hfar[64][9];
  __shared__ float bbuf[32];

  const int tid = threadIdx.x;
  const int wave = tid >> 6;  // K-slice index 0..3
  const int lane = tid & 63;
  const int lr = lane & 15;
  const int kc = lane >> 4;  // 0..3
  const int jb = blockIdx.x * 8;
  const bool has_next = (wih_next != nullptr);

  // ---- Whh preload: fp32 global -> bf16 fragments in VGPRs ----
  bf16x8 warr[2][16];
#pragma unroll
  for (int n = 0; n < 2; ++n) {
    int row = n * 16 + lr;
    int grow = (row >> 3) * H_ + jb + (row & 7);
    const float* wp = whh + (size_t)grow * H_ + wave * 512 + kc * 8;
#pragma unroll
    for (int kk = 0; kk < 16; ++kk) {
      float4 f0 = *(const float4*)(wp + kk * 32);
      float4 f1 = *(const float4*)(wp + kk * 32 + 4);
      bf16x8 w;
      w[0] = f2bf_s(f0.x); w[1] = f2bf_s(f0.y); w[2] = f2bf_s(f0.z); w[3] = f2bf_s(f0.w);
      w[4] = f2bf_s(f1.x); w[5] = f2bf_s(f1.y); w[6] = f2bf_s(f1.z); w[7] = f2bf_s(f1.w);
      warr[n][kk] = w;
    }
  }

  // ---- W_ih,next preload (same row convention), fp32 -> bf16 VGPRs ----
  bf16x8 wnarr[2][16];
  if (has_next) {
#pragma unroll
    for (int n = 0; n < 2; ++n) {
      int row = n * 16 + lr;
      int grow = (row >> 3) * H_ + jb + (row & 7);
      const float* wp = wih_next + (size_t)grow * H_ + wave * 512 + kc * 8;
#pragma unroll
      for (int kk = 0; kk < 16; ++kk) {
        float4 f0 = *(const float4*)(wp + kk * 32);
        float4 f1 = *(const float4*)(wp + kk * 32 + 4);
        bf16x8 w;
        w[0] = f2bf_s(f0.x); w[1] = f2bf_s(f0.y); w[2] = f2bf_s(f0.z); w[3] = f2bf_s(f0.w);
        w[4] = f2bf_s(f1.x); w[5] = f2bf_s(f1.y); w[6] = f2bf_s(f1.z); w[7] = f2bf_s(f1.w);
        wnarr[n][kk] = w;
      }
    }
    if (tid < 32) bbuf[tid] = bias_next[(tid >> 3) * H_ + jb + (tid & 7)];
  }
  __syncthreads();

  const uint4* const H16 = (const uint4*)hfr;
  u64* const hq = (u64*)hfr;

  const int cb = tid & 63;
  const int cp = tid >> 6;
  const int j0 = 2 * cp, j1 = 2 * cp + 1;
  float cst0 = 0.f, cst1 = 0.f;

  // xi_next writeback from red (shared by loop + epilogue)
  auto xi_writeback = [&](int tt) {
    __syncthreads();
#pragma unroll
    for (int j = 0; j < 8; ++j) {
      int e = tid + 256 * j;
      int b = e & 63, r = e >> 6;
      float v = red[0][b][r] + red[1][b][r] + red[2][b][r] + red[3][b][r] + bbuf[r];
      xi_next[((size_t)tt * G4 + (r >> 3) * H_ + jb + (r & 7)) * (size_t)B_ + b] = v;
    }
    __syncthreads();
  };

  for (int t = 0; t < T_; ++t) {
    // ---- xi loads for step t: coalesced, issued BEFORE the flag wait ----
    float xv0[4], xv1[4];
    {
      const float* xp = xi + (size_t)t * G4 * B_ + (size_t)(jb + j0) * B_ + cb;
#pragma unroll
      for (int g = 0; g < 4; ++g) {
        xv0[g] = xp[(size_t)g * H_ * B_];
        xv1[g] = xp[(size_t)g * H_ * B_ + B_];
      }
    }

    f32x4 acc[4][2] = {};
    f32x4 facc[4][2] = {};
    if (t > 0) {
      const unsigned* fp = flg + (size_t)(t - 1) * 256 + wave * 64 + lane;
      while (__hip_atomic_load(fp, __ATOMIC_RELAXED,
                               __HIP_MEMORY_SCOPE_SYSTEM) == 0u)
        __builtin_amdgcn_s_sleep(1);
      asm volatile("" ::: "memory");  // keep cached h loads below the spin

      const size_t base = ((size_t)(t - 1) * 256 + wave * 64 + kc) * 64 + lr;
      uint4 pre[2][4];
#pragma unroll
      for (int d = 0; d < 2; ++d)
#pragma unroll
        for (int m = 0; m < 4; ++m)
          pre[d][m] = H16[base + (size_t)d * 256 + m * 16];
#pragma unroll
      for (int kk = 0; kk < 16; ++kk) {
        const int slot = kk & 1;
        bf16x8 af[4];
#pragma unroll
        for (int m = 0; m < 4; ++m)
          af[m] = frag_from_u4(pre[slot][m]);
        if (kk + 2 < 16) {
#pragma unroll
          for (int m = 0; m < 4; ++m)
            pre[slot][m] = H16[base + (size_t)(kk + 2) * 256 + m * 16];
        }
#pragma unroll
        for (int m = 0; m < 4; ++m) {
          acc[m][0] = __builtin_amdgcn_mfma_f32_16x16x32_bf16(af[m], warr[0][kk], acc[m][0], 0, 0, 0);
          acc[m][1] = __builtin_amdgcn_mfma_f32_16x16x32_bf16(af[m], warr[1][kk], acc[m][1], 0, 0, 0);
        }
        if (has_next) {
#pragma unroll
          for (int m = 0; m < 4; ++m) {
            facc[m][0] = __builtin_amdgcn_mfma_f32_16x16x32_bf16(af[m], wnarr[0][kk], facc[m][0], 0, 0, 0);
            facc[m][1] = __builtin_amdgcn_mfma_f32_16x16x32_bf16(af[m], wnarr[1][kk], facc[m][1], 0, 0, 0);
          }
        }
      }
    }

    // ---- recurrent partials -> LDS; 4-way reduction in cell ----
#pragma unroll
    for (int m = 0; m < 4; ++m)
#pragma unroll
      for (int n = 0; n < 2; ++n)
#pragma unroll
        for (int j = 0; j < 4; ++j)
          red[wave][m * 16 + kc * 4 + j][n * 16 + lr] = acc[m][n][j];
    __syncthreads();

    // ---- LSTM cell ----
    {
      float s00 = red[0][cb][j0]      + red[1][cb][j0]      + red[2][cb][j0]      + red[3][cb][j0];
      float s01 = red[0][cb][8 + j0]  + red[1][cb][8 + j0]  + red[2][cb][8 + j0]  + red[3][cb][8 + j0];
      float s02 = red[0][cb][16 + j0] + red[1][cb][16 + j0] + red[2][cb][16 + j0] + red[3][cb][16 + j0];
      float s03 = red[0][cb][24 + j0] + red[1][cb][24 + j0] + red[2][cb][24 + j0] + red[3][cb][24 + j0];
      float iv = s00 + xv0[0];
      float fv = s01 + xv0[1];
      float gv = s02 + xv0[2];
      float ov = s03 + xv0[3];
      iv = 1.f / (1.f + expf(-iv));
      fv = 1.f / (1.f + expf(-fv));
      gv = tanhf(gv);
      ov = 1.f / (1.f + expf(-ov));
      cst0 = fv * cst0 + iv * gv;
      float hv0 = ov * tanhf(cst0);

      float s10 = red[0][cb][j1]      + red[1][cb][j1]      + red[2][cb][j1]      + red[3][cb][j1];
      float s11 = red[0][cb][8 + j1]  + red[1][cb][8 + j1]  + red[2][cb][8 + j1]  + red[3][cb][8 + j1];
      float s12 = red[0][cb][16 + j1] + red[1][cb][16 + j1] + red[2][cb][16 + j1] + red[3][cb][16 + j1];
      float s13 = red[0][cb][24 + j1] + red[1][cb][24 + j1] + red[2][cb][24 + j1] + red[3][cb][24 + j1];
      float iv1 = s10 + xv1[0];
      float fv1 = s11 + xv1[1];
      float gv1 = s12 + xv1[2];
      float ov1 = s13 + xv1[3];
      iv1 = 1.f / (1.f + expf(-iv1));
      fv1 = 1.f / (1.f + expf(-fv1));
      gv1 = tanhf(gv1);
      ov1 = 1.f / (1.f + expf(-ov1));
      cst1 = fv1 * cst1 + iv1 * gv1;
      float hv1 = ov1 * tanhf(cst1);

      harr[cb][cp] = (unsigned)f2bf(hv0) | ((unsigned)f2bf(hv1) << 16);
      hfar[cb][j0] = hv0;
      hfar[cb][j1] = hv1;
    }
    __syncthreads();

    // ---- wave 0: h write-through stores, then flag (incl. t=15) ----
    if (tid < B_) {
      u64 q0 = (u64)harr[tid][0] | ((u64)harr[tid][1] << 32);
      u64 q1 = (u64)harr[tid][2] | ((u64)harr[tid][3] << 32);
      u64* hp = hq + ((((size_t)t * 256 + blockIdx.x) * 64 + tid) << 1);
      __hip_atomic_store(hp, q0, __ATOMIC_RELAXED, __HIP_MEMORY_SCOPE_SYSTEM);
      __hip_atomic_store(hp + 1, q1, __ATOMIC_RELAXED, __HIP_MEMORY_SCOPE_SYSTEM);
      if (out32 != nullptr) {
        float* op = out32 + ((size_t)tid * T_ + t) * H_ + jb;
        float4 v0, v1;
        v0.x = hfar[tid][0]; v0.y = hfar[tid][1]; v0.z = hfar[tid][2]; v0.w = hfar[tid][3];
        v1.x = hfar[tid][4]; v1.y = hfar[tid][5]; v1.z = hfar[tid][6]; v1.w = hfar[tid][7];
        *(float4*)op = v0;
        *(float4*)(op + 4) = v1;
      }
    }
    if (tid == 0) {
      asm volatile("s_waitcnt vmcnt(0)" ::: "memory");  // h at coherence point
      __hip_atomic_store(flg + (size_t)t * 256 + blockIdx.x, 1u,
                         __ATOMIC_RELAXED, __HIP_MEMORY_SCOPE_SYSTEM);
    }

    // ---- OFF critical path: xi_next(t-1) reduce + store ----
    if (has_next && t > 0) {
      __syncthreads();
#pragma unroll
      for (int m = 0; m < 4; ++m)
#pragma unroll
        for (int n = 0; n < 2; ++n)
#pragma unroll
          for (int j = 0; j < 4; ++j)
            red[wave][m * 16 + kc * 4 + j][n * 16 + lr] = facc[m][n][j];
      xi_writeback(t - 1);
    }
  }

  // ---- epilogue: xi_next(15) via flag[15] ----
  if (has_next) {
    const unsigned* fp = flg + (size_t)15 * 256 + wave * 64 + lane;
    while (__hip_atomic_load(fp, __ATOMIC_RELAXED,
                             __HIP_MEMORY_SCOPE_SYSTEM) == 0u)
      __builtin_amdgcn_s_sleep(1);
    asm volatile("" ::: "memory");

    f32x4 facc[4][2] = {};
    const size_t base = ((size_t)15 * 256 + wave * 64 + kc) * 64 + lr;
    uint4 pre[2][4];
#pragma unroll
    for (int d = 0; d < 2; ++d)
#pragma unroll
      for (int m = 0; m < 4; ++m)
        pre[d][m] = H16[base + (size_t)d * 256 + m * 16];
#pragma unroll
    for (int kk = 0; kk < 16; ++kk) {
      const int slot = kk & 1;
      bf16x8 af[4];
#pragma unroll
      for (int m = 0; m < 4; ++m)
        af[m] = frag_from_u4(pre[slot][m]);
      if (kk + 2 < 16) {
#pragma unroll
        for (int m = 0; m < 4; ++m)
          pre[slot][m] = H16[base + (size_t)(kk + 2) * 256 + m * 16];
      }
#pragma unroll
      for (int m = 0; m < 4; ++m) {
        facc[m][0] = __builtin_amdgcn_mfma_f32_16x16x32_bf16(af[m], wnarr[0][kk], facc[m][0], 0, 0, 0);
        facc[m][1] = __builtin_amdgcn_mfma_f32_16x16x32_bf16(af[m], wnarr[1][kk], facc[m][1], 0, 0, 0);
      }
    }
    __syncthreads();
#pragma unroll
    for (int m = 0; m < 4; ++m)
#pragma unroll
      for (int n = 0; n < 2; ++n)
#pragma unroll
        for (int j = 0; j < 4; ++j)
          red[wave][m * 16 + kc * 4 + j][n * 16 + lr] = facc[m][n][j];
    xi_writeback(15);
  }
}

extern "C" void kernel_launch(void* const* d_in, const int* in_sizes, int n_in,
                              void* d_out, int out_size, void* d_ws, size_t ws_size,
                              hipStream_t stream) {
  const float* x    = (const float*)d_in[0];
  const float* wih0 = (const float*)d_in[1];
  const float* whh0 = (const float*)d_in[2];
  const float* bih0 = (const float*)d_in[3];
  const float* bhh0 = (const float*)d_in[4];
  const float* wihr = (const float*)d_in[5];
  const float* whhr = (const float*)d_in[6];
  const float* bihr = (const float*)d_in[7];
  const float* bhhr = (const float*)d_in[8];
  float* out = (float*)d_out;

  char* ws = (char*)d_ws;
  size_t off = 0;
  auto alloc = [&](size_t bytes) -> void* {
    void* p = ws + off;
    off += (bytes + 255) & ~(size_t)255;
    return p;
  };
  u16*      wih_b = (u16*)alloc((size_t)G4 * D0 * 2);   // layer 0 only
  float*    bias  = (float*)alloc(4ull * G4 * 4);
  float*    xiA   = (float*)alloc((size_t)T_ * B_ * G4 * 4);
  float*    xiB   = (float*)alloc((size_t)T_ * B_ * G4 * 4);
  u16*      Ax    = (u16*)alloc((size_t)T_ * B_ * D0 * 2);
  u16*      bufA  = (u16*)alloc((size_t)T_ * B_ * H_ * 2);
  u16*      bufB  = (u16*)alloc((size_t)T_ * B_ * H_ * 2);
  unsigned* flags = (unsigned*)alloc(4ull * 16 * 256 * sizeof(unsigned));

  auto cgrid = [](int n8) { int g = (n8 + 255) / 256; return g > 8192 ? 8192 : g; };

  hipMemsetAsync(flags, 0, 4ull * 16 * 256 * sizeof(unsigned), stream);

  int n8 = (G4 * D0) / 8;
  k_f32_to_bf16<<<cgrid(n8), 256, 0, stream>>>(wih0, wih_b, n8);

  k_bias<<<(4 * G4 + 255) / 256, 256, 0, stream>>>(bih0, bhh0, bihr, bhhr, bias);
  k_stage_x<<<(T_ * (D0 / 8) * B_ + 255) / 256, 256, 0, stream>>>(x, (uint4*)Ax);

  // layer 0 input projection (the only standalone GEMM)
  {
    dim3 g(G4 / 128, (T_ * B_) / 128);
    k_gemm_xi<<<g, 256, 0, stream>>>(Ax, wih_b, bias, xiA, D0, D0 / 8);
  }

  for (int l = 0; l < 4; ++l) {
    const float* whh_l = (l == 0) ? whh0 : (whhr + (size_t)(l - 1) * G4 * H_);
    u16* hbuf = (l & 1) ? bufB : bufA;
    float* o32 = (l == 3) ? out : nullptr;
    float* xi_in  = (l & 1) ? xiB : xiA;
    float* xi_out = (l & 1) ? xiA : xiB;
    const float* wih_next = (l < 3) ? (wihr + (size_t)l * G4 * H_) : nullptr;
    const float* bias_next = bias + (size_t)((l + 1) & 3) * G4;

    k_lstm_seq<<<NB, 256, 0, stream>>>(whh_l, xi_in, hbuf, o32,
                                       flags + (size_t)l * 16 * 256,
                                       wih_next, bias_next, xi_out);
  }
}

// Round 15
// 626.782 us; speedup vs baseline: 1.1303x; 1.0034x over previous
//
#include <hip/hip_runtime.h>
#include <stdint.h>

#define B_ 64
#define T_ 16
#define D0 1024
#define H_ 2048
#define G4 8192  // 4*H
#define NB 256   // persistent blocks (one per CU)

typedef unsigned short u16;
typedef unsigned long long u64;
typedef __attribute__((ext_vector_type(4))) float f32x4;
typedef __attribute__((ext_vector_type(8))) short bf16x8;

__device__ __forceinline__ u16 f2bf(float f) {
  unsigned int u = __builtin_bit_cast(unsigned int, f);
  unsigned int r = (u + 0x7FFFu + ((u >> 16) & 1u)) >> 16;
  return (u16)r;
}
__device__ __forceinline__ short f2bf_s(float f) { return (short)f2bf(f); }

__device__ __forceinline__ void gld_lds16(const void* g, void* l) {
  __builtin_amdgcn_global_load_lds(
      (const __attribute__((address_space(1))) void*)g,
      (__attribute__((address_space(3))) void*)l, 16, 0, 0);
}

__device__ __forceinline__ bf16x8 frag_from_u4(uint4 q) {
  return __builtin_bit_cast(bf16x8, q);
}

// ---------------- fp32 -> bf16 bulk conversion (RTN) ----------------
__global__ __launch_bounds__(256) void k_f32_to_bf16(
    const float* __restrict__ src, u16* __restrict__ dst, int n8) {
  int i = blockIdx.x * 256 + threadIdx.x;
  int stride = gridDim.x * 256;
  const float4* s = (const float4*)src;
  uint4* d = (uint4*)dst;
  for (; i < n8; i += stride) {
    float4 a = s[2 * i], b = s[2 * i + 1];
    uint4 o;
    o.x = f2bf(a.x) | ((unsigned)f2bf(a.y) << 16);
    o.y = f2bf(a.z) | ((unsigned)f2bf(a.w) << 16);
    o.z = f2bf(b.x) | ((unsigned)f2bf(b.y) << 16);
    o.w = f2bf(b.z) | ((unsigned)f2bf(b.w) << 16);
    d[i] = o;
  }
}

// ---------------- combined bias: b_ih + b_hh, 4 layers ----------------
__global__ __launch_bounds__(256) void k_bias(
    const float* __restrict__ bih0, const float* __restrict__ bhh0,
    const float* __restrict__ bihr, const float* __restrict__ bhhr,
    float* __restrict__ bias) {
  int i = blockIdx.x * 256 + threadIdx.x;
  if (i >= 4 * G4) return;
  int l = i >> 13, j = i & (G4 - 1);
  float a = (l == 0) ? bih0[j] : bihr[(l - 1) * G4 + j];
  float b = (l == 0) ? bhh0[j] : bhhr[(l - 1) * G4 + j];
  bias[i] = a + b;
}

// ---- stage x [B,T,D0] fp32 -> chunk layout: Ax16[(t*128 + k/8)*64 + b] ----
__global__ __launch_bounds__(256) void k_stage_x(
    const float* __restrict__ x, uint4* __restrict__ A16) {
  int i = blockIdx.x * 256 + threadIdx.x;
  if (i >= T_ * (D0 / 8) * B_) return;
  int chunk = i & 127;
  int r = i >> 7;
  int b = r & (B_ - 1), t = r >> 6;
  const float4* s = (const float4*)(x + ((size_t)(b * T_ + t)) * D0 + chunk * 8);
  float4 a0 = s[0], a1 = s[1];
  uint4 o;
  o.x = f2bf(a0.x) | ((unsigned)f2bf(a0.y) << 16);
  o.y = f2bf(a0.z) | ((unsigned)f2bf(a0.w) << 16);
  o.z = f2bf(a1.x) | ((unsigned)f2bf(a1.y) << 16);
  o.w = f2bf(a1.z) | ((unsigned)f2bf(a1.w) << 16);
  A16[((size_t)t * 128 + chunk) * 64 + b] = o;
}

// ---------------- input-projection GEMM (layer 0 only) ----------------
__global__ __launch_bounds__(256) void k_gemm_xi(
    const u16* __restrict__ A, const u16* __restrict__ W,
    const float* __restrict__ bias, float* __restrict__ C, int K, int CH) {
  __shared__ __align__(16) u16 sA[128 * 32];
  __shared__ __align__(16) u16 sB[128 * 32];
  const int tid = threadIdx.x;
  const int wave = tid >> 6;
  const int lane = tid & 63;
  const int m0 = blockIdx.y * 128;
  const int n0 = blockIdx.x * 128;
  const int wr = wave >> 1, wc = wave & 1;
  const int lr = lane & 15;
  const int kc = (lane >> 4) * 8;
  const int rowA = tid >> 2, colk = (tid & 3) * 8;

  f32x4 acc[4][4] = {};

  for (int k0 = 0; k0 < K; k0 += 32) {
#pragma unroll
    for (int iss = 0; iss < 2; ++iss) {
      int row = m0 + iss * 64 + rowA;
      int tt = row >> 6, bb = row & 63;
      int chunk = (k0 + colk) >> 3;
      gld_lds16(A + ((((size_t)tt * CH + chunk) * 64 + bb) << 3),
                sA + (iss * 64 + wave * 16) * 32);
      gld_lds16(W + (size_t)(n0 + iss * 64 + rowA) * K + k0 + colk,
                sB + (iss * 64 + wave * 16) * 32);
    }
    __syncthreads();
    bf16x8 a[4], b[4];
#pragma unroll
    for (int m = 0; m < 4; ++m)
      a[m] = *(const bf16x8*)&sA[(wr * 64 + m * 16 + lr) * 32 + kc];
#pragma unroll
    for (int n = 0; n < 4; ++n)
      b[n] = *(const bf16x8*)&sB[(wc * 64 + n * 16 + lr) * 32 + kc];
#pragma unroll
    for (int m = 0; m < 4; ++m)
#pragma unroll
      for (int n = 0; n < 4; ++n)
        acc[m][n] = __builtin_amdgcn_mfma_f32_16x16x32_bf16(a[m], b[n], acc[m][n], 0, 0, 0);
    __syncthreads();
  }

#pragma unroll
  for (int n = 0; n < 4; ++n) {
    int col = n0 + wc * 64 + n * 16 + lr;
    float bv = bias[col];
#pragma unroll
    for (int m = 0; m < 4; ++m) {
      int row0 = m0 + wr * 64 + m * 16 + ((lane >> 4) << 2);
      int t = row0 >> 6, b0 = row0 & 63;
      float4 v;
      v.x = acc[m][n][0] + bv;
      v.y = acc[m][n][1] + bv;
      v.z = acc[m][n][2] + bv;
      v.w = acc[m][n][3] + bv;
      *(float4*)&C[((size_t)t * G4 + col) * B_ + b0] = v;
    }
  }
}

// ---------------- persistent per-layer recurrent kernel ----------------
// R10 champion structure + SPLIT FLAG WAIT: wait producers [0,32) ->
// compute kk 0..7 (prefetch confined to chunks <8) -> wait [32,64)
// (hides behind first-half MFMAs) -> compute kk 8..15.
__global__ __launch_bounds__(256, 1) void k_lstm_seq(
    const float* __restrict__ whh,      // [8192][2048] fp32
    const float* __restrict__ xi,       // [T][G4][B] fp32 (bias folded)
    u16* __restrict__ hfr,              // [T][256][64] x 16B chunk layout
    float* __restrict__ out32,          // null, or [B][T][2048] fp32
    unsigned* __restrict__ flg,         // [16][256] one-shot flags, zeroed
    const float* __restrict__ wih_next, // null, or [8192][2048] fp32
    const float* __restrict__ bias_next,// [G4]
    float* __restrict__ xi_next) {      // [T][G4][B] fp32 out
  __builtin_amdgcn_fence(__ATOMIC_ACQUIRE, "agent");

  __shared__ float red[4][64][33];
  __shared__ unsigned harr[64][4];
  __shared__ float hfar[64][9];
  __shared__ float bbuf[32];

  const int tid = threadIdx.x;
  const int wave = tid >> 6;  // K-slice index 0..3
  const int lane = tid & 63;
  const int lr = lane & 15;
  const int kc = lane >> 4;  // 0..3
  const int jb = blockIdx.x * 8;
  const bool has_next = (wih_next != nullptr);

  // ---- Whh preload: fp32 global -> bf16 fragments in VGPRs ----
  bf16x8 warr[2][16];
#pragma unroll
  for (int n = 0; n < 2; ++n) {
    int row = n * 16 + lr;
    int grow = (row >> 3) * H_ + jb + (row & 7);
    const float* wp = whh + (size_t)grow * H_ + wave * 512 + kc * 8;
#pragma unroll
    for (int kk = 0; kk < 16; ++kk) {
      float4 f0 = *(const float4*)(wp + kk * 32);
      float4 f1 = *(const float4*)(wp + kk * 32 + 4);
      bf16x8 w;
      w[0] = f2bf_s(f0.x); w[1] = f2bf_s(f0.y); w[2] = f2bf_s(f0.z); w[3] = f2bf_s(f0.w);
      w[4] = f2bf_s(f1.x); w[5] = f2bf_s(f1.y); w[6] = f2bf_s(f1.z); w[7] = f2bf_s(f1.w);
      warr[n][kk] = w;
    }
  }

  // ---- W_ih,next preload (same row convention), fp32 -> bf16 VGPRs ----
  bf16x8 wnarr[2][16];
  if (has_next) {
#pragma unroll
    for (int n = 0; n < 2; ++n) {
      int row = n * 16 + lr;
      int grow = (row >> 3) * H_ + jb + (row & 7);
      const float* wp = wih_next + (size_t)grow * H_ + wave * 512 + kc * 8;
#pragma unroll
      for (int kk = 0; kk < 16; ++kk) {
        float4 f0 = *(const float4*)(wp + kk * 32);
        float4 f1 = *(const float4*)(wp + kk * 32 + 4);
        bf16x8 w;
        w[0] = f2bf_s(f0.x); w[1] = f2bf_s(f0.y); w[2] = f2bf_s(f0.z); w[3] = f2bf_s(f0.w);
        w[4] = f2bf_s(f1.x); w[5] = f2bf_s(f1.y); w[6] = f2bf_s(f1.z); w[7] = f2bf_s(f1.w);
        wnarr[n][kk] = w;
      }
    }
    if (tid < 32) bbuf[tid] = bias_next[(tid >> 3) * H_ + jb + (tid & 7)];
  }
  __syncthreads();

  const uint4* const H16 = (const uint4*)hfr;
  u64* const hq = (u64*)hfr;

  const int cb = tid & 63;
  const int cp = tid >> 6;
  const int j0 = 2 * cp, j1 = 2 * cp + 1;
  float cst0 = 0.f, cst1 = 0.f;

  // xi_next writeback from red (shared by loop + epilogue)
  auto xi_writeback = [&](int tt) {
    __syncthreads();
#pragma unroll
    for (int j = 0; j < 8; ++j) {
      int e = tid + 256 * j;
      int b = e & 63, r = e >> 6;
      float v = red[0][b][r] + red[1][b][r] + red[2][b][r] + red[3][b][r] + bbuf[r];
      xi_next[((size_t)tt * G4 + (r >> 3) * H_ + jb + (r & 7)) * (size_t)B_ + b] = v;
    }
    __syncthreads();
  };

  for (int t = 0; t < T_; ++t) {
    // ---- xi loads for step t: coalesced, issued BEFORE the flag wait ----
    float xv0[4], xv1[4];
    {
      const float* xp = xi + (size_t)t * G4 * B_ + (size_t)(jb + j0) * B_ + cb;
#pragma unroll
      for (int g = 0; g < 4; ++g) {
        xv0[g] = xp[(size_t)g * H_ * B_];
        xv1[g] = xp[(size_t)g * H_ * B_ + B_];
      }
    }

    f32x4 acc[4][2] = {};
    f32x4 facc[4][2] = {};
    if (t > 0) {
      const unsigned* fbase = flg + (size_t)(t - 1) * 256 + wave * 64;
      const size_t base = ((size_t)(t - 1) * 256 + wave * 64 + kc) * 64 + lr;
      uint4 pre[2][4];

      // ---- wait on FIRST 32 producers only (chunks 0..31 of this wave) ----
      if (lane < 32) {
        const unsigned* fp = fbase + lane;
        while (__hip_atomic_load(fp, __ATOMIC_RELAXED,
                                 __HIP_MEMORY_SCOPE_SYSTEM) == 0u)
          __builtin_amdgcn_s_sleep(1);
      }
      asm volatile("" ::: "memory");  // loads below stay below the spin

#pragma unroll
      for (int d = 0; d < 2; ++d)
#pragma unroll
        for (int m = 0; m < 4; ++m)
          pre[d][m] = H16[base + (size_t)d * 256 + m * 16];
#pragma unroll
      for (int kk = 0; kk < 8; ++kk) {
        const int slot = kk & 1;
        bf16x8 af[4];
#pragma unroll
        for (int m = 0; m < 4; ++m)
          af[m] = frag_from_u4(pre[slot][m]);
        if (kk + 2 < 8) {  // prefetch only first-half chunks
#pragma unroll
          for (int m = 0; m < 4; ++m)
            pre[slot][m] = H16[base + (size_t)(kk + 2) * 256 + m * 16];
        }
#pragma unroll
        for (int m = 0; m < 4; ++m) {
          acc[m][0] = __builtin_amdgcn_mfma_f32_16x16x32_bf16(af[m], warr[0][kk], acc[m][0], 0, 0, 0);
          acc[m][1] = __builtin_amdgcn_mfma_f32_16x16x32_bf16(af[m], warr[1][kk], acc[m][1], 0, 0, 0);
        }
        if (has_next) {
#pragma unroll
          for (int m = 0; m < 4; ++m) {
            facc[m][0] = __builtin_amdgcn_mfma_f32_16x16x32_bf16(af[m], wnarr[0][kk], facc[m][0], 0, 0, 0);
            facc[m][1] = __builtin_amdgcn_mfma_f32_16x16x32_bf16(af[m], wnarr[1][kk], facc[m][1], 0, 0, 0);
          }
        }
      }

      // ---- wait on SECOND 32 producers (usually already set) ----
      if (lane < 32) {
        const unsigned* fp = fbase + 32 + lane;
        while (__hip_atomic_load(fp, __ATOMIC_RELAXED,
                                 __HIP_MEMORY_SCOPE_SYSTEM) == 0u)
          __builtin_amdgcn_s_sleep(1);
      }
      asm volatile("" ::: "memory");

#pragma unroll
      for (int d = 0; d < 2; ++d)
#pragma unroll
        for (int m = 0; m < 4; ++m)
          pre[d][m] = H16[base + (size_t)(8 + d) * 256 + m * 16];
#pragma unroll
      for (int kk = 8; kk < 16; ++kk) {
        const int slot = kk & 1;
        bf16x8 af[4];
#pragma unroll
        for (int m = 0; m < 4; ++m)
          af[m] = frag_from_u4(pre[slot][m]);
        if (kk + 2 < 16) {
#pragma unroll
          for (int m = 0; m < 4; ++m)
            pre[slot][m] = H16[base + (size_t)(kk + 2) * 256 + m * 16];
        }
#pragma unroll
        for (int m = 0; m < 4; ++m) {
          acc[m][0] = __builtin_amdgcn_mfma_f32_16x16x32_bf16(af[m], warr[0][kk], acc[m][0], 0, 0, 0);
          acc[m][1] = __builtin_amdgcn_mfma_f32_16x16x32_bf16(af[m], warr[1][kk], acc[m][1], 0, 0, 0);
        }
        if (has_next) {
#pragma unroll
          for (int m = 0; m < 4; ++m) {
            facc[m][0] = __builtin_amdgcn_mfma_f32_16x16x32_bf16(af[m], wnarr[0][kk], facc[m][0], 0, 0, 0);
            facc[m][1] = __builtin_amdgcn_mfma_f32_16x16x32_bf16(af[m], wnarr[1][kk], facc[m][1], 0, 0, 0);
          }
        }
      }
    }

    // ---- recurrent partials -> LDS; 4-way reduction in cell ----
#pragma unroll
    for (int m = 0; m < 4; ++m)
#pragma unroll
      for (int n = 0; n < 2; ++n)
#pragma unroll
        for (int j = 0; j < 4; ++j)
          red[wave][m * 16 + kc * 4 + j][n * 16 + lr] = acc[m][n][j];
    __syncthreads();

    // ---- LSTM cell ----
    {
      float s00 = red[0][cb][j0]      + red[1][cb][j0]      + red[2][cb][j0]      + red[3][cb][j0];
      float s01 = red[0][cb][8 + j0]  + red[1][cb][8 + j0]  + red[2][cb][8 + j0]  + red[3][cb][8 + j0];
      float s02 = red[0][cb][16 + j0] + red[1][cb][16 + j0] + red[2][cb][16 + j0] + red[3][cb][16 + j0];
      float s03 = red[0][cb][24 + j0] + red[1][cb][24 + j0] + red[2][cb][24 + j0] + red[3][cb][24 + j0];
      float iv = s00 + xv0[0];
      float fv = s01 + xv0[1];
      float gv = s02 + xv0[2];
      float ov = s03 + xv0[3];
      iv = 1.f / (1.f + expf(-iv));
      fv = 1.f / (1.f + expf(-fv));
      gv = tanhf(gv);
      ov = 1.f / (1.f + expf(-ov));
      cst0 = fv * cst0 + iv * gv;
      float hv0 = ov * tanhf(cst0);

      float s10 = red[0][cb][j1]      + red[1][cb][j1]      + red[2][cb][j1]      + red[3][cb][j1];
      float s11 = red[0][cb][8 + j1]  + red[1][cb][8 + j1]  + red[2][cb][8 + j1]  + red[3][cb][8 + j1];
      float s12 = red[0][cb][16 + j1] + red[1][cb][16 + j1] + red[2][cb][16 + j1] + red[3][cb][16 + j1];
      float s13 = red[0][cb][24 + j1] + red[1][cb][24 + j1] + red[2][cb][24 + j1] + red[3][cb][24 + j1];
      float iv1 = s10 + xv1[0];
      float fv1 = s11 + xv1[1];
      float gv1 = s12 + xv1[2];
      float ov1 = s13 + xv1[3];
      iv1 = 1.f / (1.f + expf(-iv1));
      fv1 = 1.f / (1.f + expf(-fv1));
      gv1 = tanhf(gv1);
      ov1 = 1.f / (1.f + expf(-ov1));
      cst1 = fv1 * cst1 + iv1 * gv1;
      float hv1 = ov1 * tanhf(cst1);

      harr[cb][cp] = (unsigned)f2bf(hv0) | ((unsigned)f2bf(hv1) << 16);
      hfar[cb][j0] = hv0;
      hfar[cb][j1] = hv1;
    }
    __syncthreads();

    // ---- wave 0: h write-through stores, then flag (incl. t=15) ----
    if (tid < B_) {
      u64 q0 = (u64)harr[tid][0] | ((u64)harr[tid][1] << 32);
      u64 q1 = (u64)harr[tid][2] | ((u64)harr[tid][3] << 32);
      u64* hp = hq + ((((size_t)t * 256 + blockIdx.x) * 64 + tid) << 1);
      __hip_atomic_store(hp, q0, __ATOMIC_RELAXED, __HIP_MEMORY_SCOPE_SYSTEM);
      __hip_atomic_store(hp + 1, q1, __ATOMIC_RELAXED, __HIP_MEMORY_SCOPE_SYSTEM);
      if (out32 != nullptr) {
        float* op = out32 + ((size_t)tid * T_ + t) * H_ + jb;
        float4 v0, v1;
        v0.x = hfar[tid][0]; v0.y = hfar[tid][1]; v0.z = hfar[tid][2]; v0.w = hfar[tid][3];
        v1.x = hfar[tid][4]; v1.y = hfar[tid][5]; v1.z = hfar[tid][6]; v1.w = hfar[tid][7];
        *(float4*)op = v0;
        *(float4*)(op + 4) = v1;
      }
    }
    if (tid == 0) {
      asm volatile("s_waitcnt vmcnt(0)" ::: "memory");  // h at coherence point
      __hip_atomic_store(flg + (size_t)t * 256 + blockIdx.x, 1u,
                         __ATOMIC_RELAXED, __HIP_MEMORY_SCOPE_SYSTEM);
    }

    // ---- OFF critical path: xi_next(t-1) reduce + store ----
    if (has_next && t > 0) {
      __syncthreads();
#pragma unroll
      for (int m = 0; m < 4; ++m)
#pragma unroll
        for (int n = 0; n < 2; ++n)
#pragma unroll
          for (int j = 0; j < 4; ++j)
            red[wave][m * 16 + kc * 4 + j][n * 16 + lr] = facc[m][n][j];
      xi_writeback(t - 1);
    }
  }

  // ---- epilogue: xi_next(15) via flag[15] ----
  if (has_next) {
    const unsigned* fp = flg + (size_t)15 * 256 + wave * 64 + lane;
    while (__hip_atomic_load(fp, __ATOMIC_RELAXED,
                             __HIP_MEMORY_SCOPE_SYSTEM) == 0u)
      __builtin_amdgcn_s_sleep(1);
    asm volatile("" ::: "memory");

    f32x4 facc[4][2] = {};
    const size_t base = ((size_t)15 * 256 + wave * 64 + kc) * 64 + lr;
    uint4 pre[2][4];
#pragma unroll
    for (int d = 0; d < 2; ++d)
#pragma unroll
      for (int m = 0; m < 4; ++m)
        pre[d][m] = H16[base + (size_t)d * 256 + m * 16];
#pragma unroll
    for (int kk = 0; kk < 16; ++kk) {
      const int slot = kk & 1;
      bf16x8 af[4];
#pragma unroll
      for (int m = 0; m < 4; ++m)
        af[m] = frag_from_u4(pre[slot][m]);
      if (kk + 2 < 16) {
#pragma unroll
        for (int m = 0; m < 4; ++m)
          pre[slot][m] = H16[base + (size_t)(kk + 2) * 256 + m * 16];
      }
#pragma unroll
      for (int m = 0; m < 4; ++m) {
        facc[m][0] = __builtin_amdgcn_mfma_f32_16x16x32_bf16(af[m], wnarr[0][kk], facc[m][0], 0, 0, 0);
        facc[m][1] = __builtin_amdgcn_mfma_f32_16x16x32_bf16(af[m], wnarr[1][kk], facc[m][1], 0, 0, 0);
      }
    }
    __syncthreads();
#pragma unroll
    for (int m = 0; m < 4; ++m)
#pragma unroll
      for (int n = 0; n < 2; ++n)
#pragma unroll
        for (int j = 0; j < 4; ++j)
          red[wave][m * 16 + kc * 4 + j][n * 16 + lr] = facc[m][n][j];
    xi_writeback(15);
  }
}

extern "C" void kernel_launch(void* const* d_in, const int* in_sizes, int n_in,
                              void* d_out, int out_size, void* d_ws, size_t ws_size,
                              hipStream_t stream) {
  const float* x    = (const float*)d_in[0];
  const float* wih0 = (const float*)d_in[1];
  const float* whh0 = (const float*)d_in[2];
  const float* bih0 = (const float*)d_in[3];
  const float* bhh0 = (const float*)d_in[4];
  const float* wihr = (const float*)d_in[5];
  const float* whhr = (const float*)d_in[6];
  const float* bihr = (const float*)d_in[7];
  const float* bhhr = (const float*)d_in[8];
  float* out = (float*)d_out;

  char* ws = (char*)d_ws;
  size_t off = 0;
  auto alloc = [&](size_t bytes) -> void* {
    void* p = ws + off;
    off += (bytes + 255) & ~(size_t)255;
    return p;
  };
  u16*      wih_b = (u16*)alloc((size_t)G4 * D0 * 2);   // layer 0 only
  float*    bias  = (float*)alloc(4ull * G4 * 4);
  float*    xiA   = (float*)alloc((size_t)T_ * B_ * G4 * 4);
  float*    xiB   = (float*)alloc((size_t)T_ * B_ * G4 * 4);
  u16*      Ax    = (u16*)alloc((size_t)T_ * B_ * D0 * 2);
  u16*      bufA  = (u16*)alloc((size_t)T_ * B_ * H_ * 2);
  u16*      bufB  = (u16*)alloc((size_t)T_ * B_ * H_ * 2);
  unsigned* flags = (unsigned*)alloc(4ull * 16 * 256 * sizeof(unsigned));

  auto cgrid = [](int n8) { int g = (n8 + 255) / 256; return g > 8192 ? 8192 : g; };

  hipMemsetAsync(flags, 0, 4ull * 16 * 256 * sizeof(unsigned), stream);

  int n8 = (G4 * D0) / 8;
  k_f32_to_bf16<<<cgrid(n8), 256, 0, stream>>>(wih0, wih_b, n8);

  k_bias<<<(4 * G4 + 255) / 256, 256, 0, stream>>>(bih0, bhh0, bihr, bhhr, bias);
  k_stage_x<<<(T_ * (D0 / 8) * B_ + 255) / 256, 256, 0, stream>>>(x, (uint4*)Ax);

  // layer 0 input projection (the only standalone GEMM)
  {
    dim3 g(G4 / 128, (T_ * B_) / 128);
    k_gemm_xi<<<g, 256, 0, stream>>>(Ax, wih_b, bias, xiA, D0, D0 / 8);
  }

  for (int l = 0; l < 4; ++l) {
    const float* whh_l = (l == 0) ? whh0 : (whhr + (size_t)(l - 1) * G4 * H_);
    u16* hbuf = (l & 1) ? bufB : bufA;
    float* o32 = (l == 3) ? out : nullptr;
    float* xi_in  = (l & 1) ? xiB : xiA;
    float* xi_out = (l & 1) ? xiA : xiB;
    const float* wih_next = (l < 3) ? (wihr + (size_t)l * G4 * H_) : nullptr;
    const float* bias_next = bias + (size_t)((l + 1) & 3) * G4;

    k_lstm_seq<<<NB, 256, 0, stream>>>(whh_l, xi_in, hbuf, o32,
                                       flags + (size_t)l * 16 * 256,
                                       wih_next, bias_next, xi_out);
  }
}